// Round 5
// baseline (971.807 us; speedup 1.0000x reference)
//
#include <hip/hip_runtime.h>
#include <stdint.h>

typedef short bf16x8 __attribute__((ext_vector_type(8)));
typedef short s16x4 __attribute__((ext_vector_type(4)));
typedef float f32x4 __attribute__((ext_vector_type(4)));
typedef unsigned int u32;

#define EPS_A 1e-8f
#define THR_A 1e-6f
#define NN 8192

static __device__ __forceinline__ short f2bf(float f) {
  u32 u = __float_as_uint(f);
  u = u + 0x7FFFu + ((u >> 16) & 1u);   // RNE, no NaN inputs here
  return (short)(u >> 16);
}
static __device__ __forceinline__ float bf2f(short s) {
  return __uint_as_float(((u32)(unsigned short)s) << 16);
}

// ---- P1: single pass over M: transpose-cast -> Mt bf16 [i][j], colsum, colmax
__global__ __launch_bounds__(256) void k_prep_mt(
    const float* __restrict__ M, short* __restrict__ Mt,
    float* __restrict__ colsum, u32* __restrict__ colmax)
{
  __shared__ __align__(16) short tile[256 * 66];  // [i_local][j_local], stride 66
  const int t = threadIdx.x;
  const int i0 = blockIdx.x * 256;
  const int j0 = blockIdx.y * 64;
  const int i = i0 + t;
  float s = 0.f, mx = 0.f;
  #pragma unroll 4
  for (int jj = 0; jj < 64; ++jj) {
    float v = M[(size_t)(j0 + jj) * NN + i];    // coalesced: t -> i
    s += v;
    mx = fmaxf(mx, v);
    tile[t * 66 + jj] = f2bf(v);
  }
  atomicAdd(&colsum[i], s);
  atomicMax(&colmax[i], __float_as_uint(mx));   // M >= 0, uint order == float order
  __syncthreads();
  #pragma unroll
  for (int p = 0; p < 8; ++p) {
    const int r = p * 32 + (t >> 3);
    const int c = t & 7;
    const u32* src = (const u32*)((const char*)tile + r * 132 + c * 16);
    int4 w = make_int4(src[0], src[1], src[2], src[3]);
    *(int4*)((char*)Mt + (((size_t)(i0 + r) * NN + j0) * 2 + c * 16)) = w;
  }
}

// ---- cast node_features fp32 -> bf16 into Acat1 cols 512:768 (ld 768)
__global__ __launch_bounds__(256) void k_cast_nf(const float* __restrict__ nf,
                                                 short* __restrict__ acat) {
  const int idx = blockIdx.x * 256 + threadIdx.x;
  const float4 v = ((const float4*)nf)[idx];
  const int i = idx >> 6;
  const int c = (idx & 63) * 4;
  s16x4 o;
  o.x = f2bf(v.x); o.y = f2bf(v.y); o.z = f2bf(v.z); o.w = f2bf(v.w);
  *(s16x4*)&acat[(size_t)i * 768 + 512 + c] = o;
}

// ---- generic small transpose-cast: out[c*ldo + r] = bf16(in[r*C + c])
__global__ __launch_bounds__(256) void k_tcast(const float* __restrict__ in, int R, int C,
                                               short* __restrict__ out, int ldo) {
  const int idx = blockIdx.x * 256 + threadIdx.x;
  if (idx >= R * C) return;
  const int r = idx / C, c = idx % C;
  out[(size_t)c * ldo + r] = f2bf(in[idx]);
}

// ---- uniform GEMM: C[M,N] = A[M,K] @ B[N,K]^T, bf16 in, fp32 acc
// BM x BN tile, BK=64, 4 waves as 2x2 (wave tile (BM/2) x (BN/2)),
// 16B-granule XOR-swizzled LDS (conflict-free), XCD-swizzled blocks.
// EPI 0: += bias0[m], bf16 out   EPI 1: agg epilogue, bf16 out
// EPI 2: += bias0[n]+bias1[n], fp32 out
template <int BM, int BN, int EPI>
__device__ __forceinline__ void gemm_body(
    const short* __restrict__ A, const short* __restrict__ B, int K, int ldA, int ldB,
    void* __restrict__ Cout, int ldC,
    const float* __restrict__ bias0, const float* __restrict__ bias1,
    const float* __restrict__ colsum, const u32* __restrict__ colmax,
    const short* __restrict__ Tfall)
{
  constexpr int MI = BM / 32;               // acc rows per wave (frag-16 units)
  constexpr int NI = BN / 32;               // acc cols per wave
  __shared__ __align__(16) short As[BM * 64];
  __shared__ __align__(16) short Bs[BN * 64];
  const int t = threadIdx.x;

  // XCD-aware block swizzle (nwg % 8 == 0 for all our launches)
  const int gx = gridDim.x;
  int flat = blockIdx.y * gx + blockIdx.x;
  const int cpx = (gx * gridDim.y) >> 3;
  flat = (flat & 7) * cpx + (flat >> 3);
  const int bx = flat % gx, by = flat / gx;
  const int m0 = by * BM, n0 = bx * BN;

  const int wid = t >> 6, l = t & 63;
  const int wr = wid >> 1, wc = wid & 1;
  const int lr = l & 15, lk = l >> 4;

  f32x4 acc[MI][NI] = {};

  // staging: 16B granules; row = p*32 + (t>>3), slot = t&7 (8 x 16B per 128B row)
  const int srow = t >> 3;                  // 0..31
  const int sslot = t & 7;
  const short* gA = A + (size_t)(m0 + srow) * ldA + sslot * 8;
  const short* gB = B + (size_t)(n0 + srow) * ldB + sslot * 8;
  const int wslot = sslot ^ (srow & 7);     // XOR swizzle (row bits 0..2)

  for (int k0 = 0; k0 < K; k0 += 64) {
    int4 va[MI], vb[NI];
    #pragma unroll
    for (int p = 0; p < MI; ++p)
      va[p] = *(const int4*)(gA + (size_t)p * 32 * ldA + k0);
    #pragma unroll
    for (int p = 0; p < NI; ++p)
      vb[p] = *(const int4*)(gB + (size_t)p * 32 * ldB + k0);
    __syncthreads();
    #pragma unroll
    for (int p = 0; p < MI; ++p)
      *(int4*)&As[((p * 32 + srow) * 8 + wslot) * 8] = va[p];
    #pragma unroll
    for (int p = 0; p < NI; ++p)
      *(int4*)&Bs[((p * 32 + srow) * 8 + wslot) * 8] = vb[p];
    __syncthreads();

    #pragma unroll
    for (int ks = 0; ks < 2; ++ks) {
      bf16x8 av[MI], bv[NI];
      #pragma unroll
      for (int mi = 0; mi < MI; ++mi) {
        const int row = wr * (BM / 2) + mi * 16 + lr;
        const int slot = (ks * 4 + lk) ^ (row & 7);
        av[mi] = *(const bf16x8*)&As[(row * 8 + slot) * 8];
      }
      #pragma unroll
      for (int ni = 0; ni < NI; ++ni) {
        const int row = wc * (BN / 2) + ni * 16 + lr;
        const int slot = (ks * 4 + lk) ^ (row & 7);
        bv[ni] = *(const bf16x8*)&Bs[(row * 8 + slot) * 8];
      }
      #pragma unroll
      for (int mi = 0; mi < MI; ++mi)
        #pragma unroll
        for (int ni = 0; ni < NI; ++ni)
          acc[mi][ni] = __builtin_amdgcn_mfma_f32_16x16x32_bf16(av[mi], bv[ni], acc[mi][ni], 0, 0, 0);
    }
  }

  #pragma unroll
  for (int mi = 0; mi < MI; ++mi) {
    #pragma unroll
    for (int r = 0; r < 4; ++r) {
      const int m = m0 + wr * (BM / 2) + mi * 16 + lk * 4 + r;
      float b0 = 0.f, rcw = 0.f;
      bool he = true;
      if (EPI == 0) b0 = bias0[m];
      if (EPI == 1) {
        const float cs = colsum[m];
        const float rc = 1.f / (cs + EPS_A);
        const float wsum = cs * rc;
        rcw = rc / (wsum + EPS_A);
        he = __uint_as_float(colmax[m]) * rc > THR_A;
      }
      #pragma unroll
      for (int ni = 0; ni < NI; ++ni) {
        const int n = n0 + wc * (BN / 2) + ni * 16 + lr;
        float v = acc[mi][ni][r];
        if (EPI == 0) {
          v += b0;
          ((short*)Cout)[(size_t)m * ldC + n] = f2bf(v);
        } else if (EPI == 1) {
          v *= rcw;
          if (__ballot(!he))                 // wave-uniform skip: fallback is rare
            if (!he) v = bf2f(Tfall[(size_t)n * NN + m]);
          ((short*)Cout)[(size_t)m * ldC + n] = f2bf(v);
        } else {
          v += bias0[n] + bias1[n];
          ((float*)Cout)[(size_t)m * ldC + n] = v;
        }
      }
    }
  }
}

__global__ __launch_bounds__(256, 2) void k_gemm_bias_w(
    const short* __restrict__ A, const short* __restrict__ B, int K, int ldA, int ldB,
    void* __restrict__ C, int ldC, const float* __restrict__ bias0) {
  gemm_body<64, 128, 0>(A, B, K, ldA, ldB, C, ldC, bias0, nullptr, nullptr, nullptr, nullptr);
}
__global__ __launch_bounds__(256, 2) void k_gemm_bias_n(
    const short* __restrict__ A, const short* __restrict__ B, int K, int ldA, int ldB,
    void* __restrict__ C, int ldC, const float* __restrict__ bias0) {
  gemm_body<64, 64, 0>(A, B, K, ldA, ldB, C, ldC, bias0, nullptr, nullptr, nullptr, nullptr);
}
__global__ __launch_bounds__(256, 2) void k_gemm_agg_w(
    const short* __restrict__ A, const short* __restrict__ B, int K, int ldA, int ldB,
    void* __restrict__ C, int ldC, const float* __restrict__ colsum,
    const u32* __restrict__ colmax, const short* __restrict__ Tfall) {
  gemm_body<64, 128, 1>(A, B, K, ldA, ldB, C, ldC, nullptr, nullptr, colsum, colmax, Tfall);
}
__global__ __launch_bounds__(256, 2) void k_gemm_agg_n(
    const short* __restrict__ A, const short* __restrict__ B, int K, int ldA, int ldB,
    void* __restrict__ C, int ldC, const float* __restrict__ colsum,
    const u32* __restrict__ colmax, const short* __restrict__ Tfall) {
  gemm_body<64, 64, 1>(A, B, K, ldA, ldB, C, ldC, nullptr, nullptr, colsum, colmax, Tfall);
}
__global__ __launch_bounds__(256, 2) void k_gemm_out_w(
    const short* __restrict__ A, const short* __restrict__ B, int K, int ldA, int ldB,
    void* __restrict__ C, int ldC, const float* __restrict__ bias0,
    const float* __restrict__ bias1) {
  gemm_body<64, 128, 2>(A, B, K, ldA, ldB, C, ldC, bias0, bias1, nullptr, nullptr, nullptr);
}
__global__ __launch_bounds__(256, 2) void k_gemm_out_n(
    const short* __restrict__ A, const short* __restrict__ B, int K, int ldA, int ldB,
    void* __restrict__ C, int ldC, const float* __restrict__ bias0,
    const float* __restrict__ bias1) {
  gemm_body<64, 64, 2>(A, B, K, ldA, ldB, C, ldC, bias0, bias1, nullptr, nullptr, nullptr);
}

// ---- row LayerNorm + ReLU, fp32 in.  MODE 0: bf16 out (ld-strided), MODE 1: fp32 out
template <int MODE>
__device__ __forceinline__ void ln_relu_body(
    const float* __restrict__ X, int W,
    const float* __restrict__ g, const float* __restrict__ be,
    void* __restrict__ out, int ldo)
{
  const int row = blockIdx.x;
  const int t = threadIdx.x;
  const float* x = X + (size_t)row * W;
  float v0 = x[t], v1 = 0.f;
  float s = v0, ss = v0 * v0;
  if (W == 512) { v1 = x[t + 256]; s += v1; ss += v1 * v1; }
  #pragma unroll
  for (int off = 32; off; off >>= 1) {
    s += __shfl_down(s, off);
    ss += __shfl_down(ss, off);
  }
  __shared__ float red[8];
  const int wid = t >> 6;
  if ((t & 63) == 0) { red[wid] = s; red[4 + wid] = ss; }
  __syncthreads();
  s = red[0] + red[1] + red[2] + red[3];
  ss = red[4] + red[5] + red[6] + red[7];
  const float mu = s / W;
  const float var = ss / W - mu * mu;
  const float sc = rsqrtf(var + 1e-5f);
  float y = fmaxf((v0 - mu) * sc * g[t] + be[t], 0.f);
  if (MODE == 0) ((short*)out)[(size_t)row * ldo + t] = f2bf(y);
  else           ((float*)out)[(size_t)row * ldo + t] = y;
  if (W == 512) {
    float y1 = fmaxf((v1 - mu) * sc * g[t + 256] + be[t + 256], 0.f);
    if (MODE == 0) ((short*)out)[(size_t)row * ldo + t + 256] = f2bf(y1);
    else           ((float*)out)[(size_t)row * ldo + t + 256] = y1;
  }
}

__global__ __launch_bounds__(256) void k_ln_relu_bf16(
    const float* __restrict__ X, int W, const float* __restrict__ g,
    const float* __restrict__ be, short* __restrict__ out, int ldo) {
  ln_relu_body<0>(X, W, g, be, out, ldo);
}
__global__ __launch_bounds__(256) void k_ln_relu_f32(
    const float* __restrict__ X, int W, const float* __restrict__ g,
    const float* __restrict__ be, float* __restrict__ out, int ldo) {
  ln_relu_body<1>(X, W, g, be, out, ldo);
}

extern "C" void kernel_launch(void* const* d_in, const int* in_sizes, int n_in,
                              void* d_out, int out_size, void* d_ws, size_t ws_size,
                              hipStream_t stream) {
  const float* nf      = (const float*)d_in[0];
  const float* Mob     = (const float*)d_in[1];
  const float* W_in1   = (const float*)d_in[2];
  const float* b_in1   = (const float*)d_in[3];
  const float* W_out1  = (const float*)d_in[4];
  const float* b_out1  = (const float*)d_in[5];
  const float* W_self1 = (const float*)d_in[6];
  const float* b_self1 = (const float*)d_in[7];
  const float* g1      = (const float*)d_in[8];
  const float* be1     = (const float*)d_in[9];
  const float* W_in2   = (const float*)d_in[10];
  const float* b_in2   = (const float*)d_in[11];
  const float* W_out2  = (const float*)d_in[12];
  const float* b_out2  = (const float*)d_in[13];
  const float* W_self2 = (const float*)d_in[14];
  const float* b_self2 = (const float*)d_in[15];
  const float* g2      = (const float*)d_in[16];
  const float* be2     = (const float*)d_in[17];

  char* ws = (char*)d_ws;
  float* colsum = (float*)(ws);                       // 8192 f32
  u32*   colmax = (u32*)(ws + 32768);                 // 8192 u32
  short* Mt     = (short*)(ws + 65536);               // [8192][8192] bf16 (unnormalized W^T)
  short* Acat1  = (short*)(ws + 134283264);           // [8192][768]: [agg1(512) | nf(256)]
  short* T1t    = (short*)(ws + 146866176);           // [512][8192]
  float* C2     = (float*)(ws + 155254784);           // [8192][512] f32 (reused [8192][256])
  short* Acat2  = (short*)(ws + 172032000);           // [8192][768]: [agg2(256) | h1(512)]
  short* T2t    = (short*)(ws + 184614912);           // [256][8192]
  short* Bcat1  = (short*)(ws + 188809216);           // [512][768]: [Wout1^T | Wself1^T]
  short* Bcat2  = (short*)(ws + 189595648);           // [256][768]: [Wout2^T | Wself2^T]
  short* Win1t  = (short*)(ws + 189988864);           // [512][256]
  short* Win2t  = (short*)(ws + 190251008);           // [256][512]

  hipMemsetAsync(ws, 0, 65536, stream);  // zero colsum + colmax every call

  k_prep_mt<<<dim3(32, 128), 256, 0, stream>>>(Mob, Mt, colsum, colmax);
  k_cast_nf<<<2048, 256, 0, stream>>>(nf, Acat1);
  k_tcast<<<512, 256, 0, stream>>>(W_in1, 256, 512, Win1t, 256);
  k_tcast<<<1024, 256, 0, stream>>>(W_out1, 512, 512, Bcat1, 768);
  k_tcast<<<512, 256, 0, stream>>>(W_self1, 256, 512, Bcat1 + 512, 768);
  k_tcast<<<512, 256, 0, stream>>>(W_in2, 512, 256, Win2t, 512);
  k_tcast<<<256, 256, 0, stream>>>(W_out2, 256, 256, Bcat2, 768);
  k_tcast<<<512, 256, 0, stream>>>(W_self2, 512, 256, Bcat2 + 256, 768);

  // layer 1 (BN=128 variants; all grids = 512 blocks)
  k_gemm_bias_w<<<dim3(64, 8), 256, 0, stream>>>(Win1t, Acat1 + 512, 256, 256, 768,
                                                 T1t, NN, b_in1);
  k_gemm_agg_w<<<dim3(4, 128), 256, 0, stream>>>(Mt, T1t, NN, NN, NN,
                                                 Acat1, 768, colsum, colmax, T1t);
  k_gemm_out_w<<<dim3(4, 128), 256, 0, stream>>>(Acat1, Bcat1, 768, 768, 768,
                                                 C2, 512, b_out1, b_self1);
  k_ln_relu_bf16<<<8192, 256, 0, stream>>>(C2, 512, g1, be1, Acat2 + 256, 768);

  // layer 2 (BN=64 variants; all grids = 512 blocks)
  k_gemm_bias_n<<<dim3(128, 4), 256, 0, stream>>>(Win2t, Acat2 + 256, 512, 512, 768,
                                                  T2t, NN, b_in2);
  k_gemm_agg_n<<<dim3(4, 128), 256, 0, stream>>>(Mt, T2t, NN, NN, NN,
                                                 Acat2, 768, colsum, colmax, T2t);
  k_gemm_out_n<<<dim3(4, 128), 256, 0, stream>>>(Acat2, Bcat2, 768, 768, 768,
                                                 C2, 256, b_out2, b_self2);
  k_ln_relu_f32<<<8192, 256, 0, stream>>>(C2, 256, g2, be2, (float*)d_out, 256);
}

// Round 6
// 447.174 us; speedup vs baseline: 2.1732x; 2.1732x over previous
//
#include <hip/hip_runtime.h>
#include <stdint.h>

typedef short bf16x8 __attribute__((ext_vector_type(8)));
typedef short s16x4 __attribute__((ext_vector_type(4)));
typedef float f32x4 __attribute__((ext_vector_type(4)));
typedef unsigned int u32;

#define EPS_A 1e-8f
#define THR_A 1e-6f
#define NN 8192

static __device__ __forceinline__ short f2bf(float f) {
  u32 u = __float_as_uint(f);
  u = u + 0x7FFFu + ((u >> 16) & 1u);   // RNE, no NaN inputs here
  return (short)(u >> 16);
}
static __device__ __forceinline__ float bf2f(short s) {
  return __uint_as_float(((u32)(unsigned short)s) << 16);
}

// ---- P1: single pass over M: transpose-cast -> Mt bf16 [i][j], colsum, colmax
__global__ __launch_bounds__(256) void k_prep_mt(
    const float* __restrict__ M, short* __restrict__ Mt,
    float* __restrict__ colsum, u32* __restrict__ colmax)
{
  __shared__ __align__(16) short tile[256 * 66];  // [i_local][j_local], stride 66
  const int t = threadIdx.x;
  const int i0 = blockIdx.x * 256;
  const int j0 = blockIdx.y * 64;
  const int i = i0 + t;
  float s = 0.f, mx = 0.f;
  #pragma unroll 4
  for (int jj = 0; jj < 64; ++jj) {
    float v = M[(size_t)(j0 + jj) * NN + i];    // coalesced: t -> i
    s += v;
    mx = fmaxf(mx, v);
    tile[t * 66 + jj] = f2bf(v);
  }
  atomicAdd(&colsum[i], s);
  atomicMax(&colmax[i], __float_as_uint(mx));   // M >= 0, uint order == float order
  __syncthreads();
  #pragma unroll
  for (int p = 0; p < 8; ++p) {
    const int r = p * 32 + (t >> 3);
    const int c = t & 7;
    const u32* src = (const u32*)((const char*)tile + r * 132 + c * 16);
    int4 w = make_int4(src[0], src[1], src[2], src[3]);
    *(int4*)((char*)Mt + (((size_t)(i0 + r) * NN + j0) * 2 + c * 16)) = w;
  }
}

// ---- cast node_features fp32 -> bf16 into Acat1 cols 512:768 (ld 768)
__global__ __launch_bounds__(256) void k_cast_nf(const float* __restrict__ nf,
                                                 short* __restrict__ acat) {
  const int idx = blockIdx.x * 256 + threadIdx.x;
  const float4 v = ((const float4*)nf)[idx];
  const int i = idx >> 6;
  const int c = (idx & 63) * 4;
  s16x4 o;
  o.x = f2bf(v.x); o.y = f2bf(v.y); o.z = f2bf(v.z); o.w = f2bf(v.w);
  *(s16x4*)&acat[(size_t)i * 768 + 512 + c] = o;
}

// ---- generic small transpose-cast: out[c*ldo + r] = bf16(in[r*C + c])
__global__ __launch_bounds__(256) void k_tcast(const float* __restrict__ in, int R, int C,
                                               short* __restrict__ out, int ldo) {
  const int idx = blockIdx.x * 256 + threadIdx.x;
  if (idx >= R * C) return;
  const int r = idx / C, c = idx % C;
  out[(size_t)c * ldo + r] = f2bf(in[idx]);
}

// ---- uniform GEMM: C[M,N] = A[M,K] @ B[N,K]^T, bf16 in, fp32 acc
// 64 x BN tile, BK=32 (round-4 loop skeleton: precomputed pointers, +k0 only),
// padded LDS rows (40 shorts = 80 B -> <=2-way bank conflicts), XCD block swizzle.
// EPI 0: += bias0[m], bf16 out   EPI 1: agg epilogue, bf16 out
// EPI 2: += bias0[n]+bias1[n], fp32 out
template <int BN, int EPI>
__device__ __forceinline__ void gemm_body(
    const short* __restrict__ A, const short* __restrict__ B, int K, int ldA, int ldB,
    void* __restrict__ Cout, int ldC,
    const float* __restrict__ bias0, const float* __restrict__ bias1,
    const float* __restrict__ colsum, const u32* __restrict__ colmax,
    const short* __restrict__ Tfall)
{
  constexpr int BM = 64;
  constexpr int MI = BM / 32;               // 2
  constexpr int NI = BN / 32;               // 4 (BN=128) or 2 (BN=64)
  constexpr int LDP = 40;                   // padded row stride in shorts (80 B)
  __shared__ __align__(16) short As[BM * LDP];
  __shared__ __align__(16) short Bs[BN * LDP];
  const int t = threadIdx.x;

  // XCD-aware block swizzle (all launches have nwg % 8 == 0)
  const int gx = gridDim.x;
  int flat = blockIdx.y * gx + blockIdx.x;
  const int cpx = (gx * gridDim.y) >> 3;
  flat = (flat & 7) * cpx + (flat >> 3);
  const int bx = flat % gx, by = flat / gx;
  const int m0 = by * BM, n0 = bx * BN;

  const int wid = t >> 6, l = t & 63;
  const int wr = wid >> 1, wc = wid & 1;    // 2x2 waves, (BM/2) x (BN/2) each
  const int lr = l & 15, lk = l >> 4;

  f32x4 acc[MI][NI] = {};

  const int sr = t >> 2;                    // staging row 0..63
  const int sc = (t & 3) * 8;               // short col 0/8/16/24
  const short* gA0 = A + (size_t)(m0 + sr) * ldA + sc;
  const short* gB0 = B + (size_t)(n0 + sr) * ldB + sc;
  const short* gB1 = gB0 + (size_t)64 * ldB;

  for (int k0 = 0; k0 < K; k0 += 32) {
    const int4 a0 = *(const int4*)(gA0 + k0);
    const int4 b0 = *(const int4*)(gB0 + k0);
    int4 b1 = make_int4(0, 0, 0, 0);
    if (NI == 4) b1 = *(const int4*)(gB1 + k0);
    __syncthreads();                        // protect previous iteration's reads
    *(int4*)&As[sr * LDP + sc] = a0;
    *(int4*)&Bs[sr * LDP + sc] = b0;
    if (NI == 4) *(int4*)&Bs[(64 + sr) * LDP + sc] = b1;
    __syncthreads();

    bf16x8 av[MI], bv[NI];
    #pragma unroll
    for (int mi = 0; mi < MI; ++mi)
      av[mi] = *(const bf16x8*)&As[(wr * (BM / 2) + mi * 16 + lr) * LDP + lk * 8];
    #pragma unroll
    for (int ni = 0; ni < NI; ++ni)
      bv[ni] = *(const bf16x8*)&Bs[(wc * (BN / 2) + ni * 16 + lr) * LDP + lk * 8];
    #pragma unroll
    for (int mi = 0; mi < MI; ++mi)
      #pragma unroll
      for (int ni = 0; ni < NI; ++ni)
        acc[mi][ni] = __builtin_amdgcn_mfma_f32_16x16x32_bf16(av[mi], bv[ni], acc[mi][ni], 0, 0, 0);
  }

  #pragma unroll
  for (int mi = 0; mi < MI; ++mi) {
    #pragma unroll
    for (int r = 0; r < 4; ++r) {
      const int m = m0 + wr * (BM / 2) + mi * 16 + lk * 4 + r;
      float b0 = 0.f, rcw = 0.f;
      bool he = true;
      if (EPI == 0) b0 = bias0[m];
      if (EPI == 1) {
        const float cs = colsum[m];
        const float rc = 1.f / (cs + EPS_A);
        const float wsum = cs * rc;
        rcw = rc / (wsum + EPS_A);
        he = __uint_as_float(colmax[m]) * rc > THR_A;
      }
      #pragma unroll
      for (int ni = 0; ni < NI; ++ni) {
        const int n = n0 + wc * (BN / 2) + ni * 16 + lr;
        float v = acc[mi][ni][r];
        if (EPI == 0) {
          v += b0;
          ((short*)Cout)[(size_t)m * ldC + n] = f2bf(v);
        } else if (EPI == 1) {
          v *= rcw;
          if (__ballot(!he))               // wave-uniform skip: fallback is rare
            if (!he) v = bf2f(Tfall[(size_t)n * NN + m]);
          ((short*)Cout)[(size_t)m * ldC + n] = f2bf(v);
        } else {
          v += bias0[n] + bias1[n];
          ((float*)Cout)[(size_t)m * ldC + n] = v;
        }
      }
    }
  }
}

__global__ __launch_bounds__(256) void k_gemm_bias_w(
    const short* __restrict__ A, const short* __restrict__ B, int K, int ldA, int ldB,
    void* __restrict__ C, int ldC, const float* __restrict__ bias0) {
  gemm_body<128, 0>(A, B, K, ldA, ldB, C, ldC, bias0, nullptr, nullptr, nullptr, nullptr);
}
__global__ __launch_bounds__(256) void k_gemm_bias_n(
    const short* __restrict__ A, const short* __restrict__ B, int K, int ldA, int ldB,
    void* __restrict__ C, int ldC, const float* __restrict__ bias0) {
  gemm_body<64, 0>(A, B, K, ldA, ldB, C, ldC, bias0, nullptr, nullptr, nullptr, nullptr);
}
__global__ __launch_bounds__(256) void k_gemm_agg_w(
    const short* __restrict__ A, const short* __restrict__ B, int K, int ldA, int ldB,
    void* __restrict__ C, int ldC, const float* __restrict__ colsum,
    const u32* __restrict__ colmax, const short* __restrict__ Tfall) {
  gemm_body<128, 1>(A, B, K, ldA, ldB, C, ldC, nullptr, nullptr, colsum, colmax, Tfall);
}
__global__ __launch_bounds__(256) void k_gemm_agg_n(
    const short* __restrict__ A, const short* __restrict__ B, int K, int ldA, int ldB,
    void* __restrict__ C, int ldC, const float* __restrict__ colsum,
    const u32* __restrict__ colmax, const short* __restrict__ Tfall) {
  gemm_body<64, 1>(A, B, K, ldA, ldB, C, ldC, nullptr, nullptr, colsum, colmax, Tfall);
}
__global__ __launch_bounds__(256) void k_gemm_out_w(
    const short* __restrict__ A, const short* __restrict__ B, int K, int ldA, int ldB,
    void* __restrict__ C, int ldC, const float* __restrict__ bias0,
    const float* __restrict__ bias1) {
  gemm_body<128, 2>(A, B, K, ldA, ldB, C, ldC, bias0, bias1, nullptr, nullptr, nullptr);
}
__global__ __launch_bounds__(256) void k_gemm_out_n(
    const short* __restrict__ A, const short* __restrict__ B, int K, int ldA, int ldB,
    void* __restrict__ C, int ldC, const float* __restrict__ bias0,
    const float* __restrict__ bias1) {
  gemm_body<64, 2>(A, B, K, ldA, ldB, C, ldC, bias0, bias1, nullptr, nullptr, nullptr);
}

// ---- row LayerNorm + ReLU, fp32 in.  MODE 0: bf16 out (ld-strided), MODE 1: fp32 out
template <int MODE>
__device__ __forceinline__ void ln_relu_body(
    const float* __restrict__ X, int W,
    const float* __restrict__ g, const float* __restrict__ be,
    void* __restrict__ out, int ldo)
{
  const int row = blockIdx.x;
  const int t = threadIdx.x;
  const float* x = X + (size_t)row * W;
  float v0 = x[t], v1 = 0.f;
  float s = v0, ss = v0 * v0;
  if (W == 512) { v1 = x[t + 256]; s += v1; ss += v1 * v1; }
  #pragma unroll
  for (int off = 32; off; off >>= 1) {
    s += __shfl_down(s, off);
    ss += __shfl_down(ss, off);
  }
  __shared__ float red[8];
  const int wid = t >> 6;
  if ((t & 63) == 0) { red[wid] = s; red[4 + wid] = ss; }
  __syncthreads();
  s = red[0] + red[1] + red[2] + red[3];
  ss = red[4] + red[5] + red[6] + red[7];
  const float mu = s / W;
  const float var = ss / W - mu * mu;
  const float sc = rsqrtf(var + 1e-5f);
  float y = fmaxf((v0 - mu) * sc * g[t] + be[t], 0.f);
  if (MODE == 0) ((short*)out)[(size_t)row * ldo + t] = f2bf(y);
  else           ((float*)out)[(size_t)row * ldo + t] = y;
  if (W == 512) {
    float y1 = fmaxf((v1 - mu) * sc * g[t + 256] + be[t + 256], 0.f);
    if (MODE == 0) ((short*)out)[(size_t)row * ldo + t + 256] = f2bf(y1);
    else           ((float*)out)[(size_t)row * ldo + t + 256] = y1;
  }
}

__global__ __launch_bounds__(256) void k_ln_relu_bf16(
    const float* __restrict__ X, int W, const float* __restrict__ g,
    const float* __restrict__ be, short* __restrict__ out, int ldo) {
  ln_relu_body<0>(X, W, g, be, out, ldo);
}
__global__ __launch_bounds__(256) void k_ln_relu_f32(
    const float* __restrict__ X, int W, const float* __restrict__ g,
    const float* __restrict__ be, float* __restrict__ out, int ldo) {
  ln_relu_body<1>(X, W, g, be, out, ldo);
}

extern "C" void kernel_launch(void* const* d_in, const int* in_sizes, int n_in,
                              void* d_out, int out_size, void* d_ws, size_t ws_size,
                              hipStream_t stream) {
  const float* nf      = (const float*)d_in[0];
  const float* Mob     = (const float*)d_in[1];
  const float* W_in1   = (const float*)d_in[2];
  const float* b_in1   = (const float*)d_in[3];
  const float* W_out1  = (const float*)d_in[4];
  const float* b_out1  = (const float*)d_in[5];
  const float* W_self1 = (const float*)d_in[6];
  const float* b_self1 = (const float*)d_in[7];
  const float* g1      = (const float*)d_in[8];
  const float* be1     = (const float*)d_in[9];
  const float* W_in2   = (const float*)d_in[10];
  const float* b_in2   = (const float*)d_in[11];
  const float* W_out2  = (const float*)d_in[12];
  const float* b_out2  = (const float*)d_in[13];
  const float* W_self2 = (const float*)d_in[14];
  const float* b_self2 = (const float*)d_in[15];
  const float* g2      = (const float*)d_in[16];
  const float* be2     = (const float*)d_in[17];

  char* ws = (char*)d_ws;
  float* colsum = (float*)(ws);                       // 8192 f32
  u32*   colmax = (u32*)(ws + 32768);                 // 8192 u32
  short* Mt     = (short*)(ws + 65536);               // [8192][8192] bf16 (unnormalized W^T)
  short* Acat1  = (short*)(ws + 134283264);           // [8192][768]: [agg1(512) | nf(256)]
  short* T1t    = (short*)(ws + 146866176);           // [512][8192]
  float* C2     = (float*)(ws + 155254784);           // [8192][512] f32 (reused [8192][256])
  short* Acat2  = (short*)(ws + 172032000);           // [8192][768]: [agg2(256) | h1(512)]
  short* T2t    = (short*)(ws + 184614912);           // [256][8192]
  short* Bcat1  = (short*)(ws + 188809216);           // [512][768]: [Wout1^T | Wself1^T]
  short* Bcat2  = (short*)(ws + 189595648);           // [256][768]: [Wout2^T | Wself2^T]
  short* Win1t  = (short*)(ws + 189988864);           // [512][256]
  short* Win2t  = (short*)(ws + 190251008);           // [256][512]

  hipMemsetAsync(ws, 0, 65536, stream);  // zero colsum + colmax every call

  k_prep_mt<<<dim3(32, 128), 256, 0, stream>>>(Mob, Mt, colsum, colmax);
  k_cast_nf<<<2048, 256, 0, stream>>>(nf, Acat1);
  k_tcast<<<512, 256, 0, stream>>>(W_in1, 256, 512, Win1t, 256);
  k_tcast<<<1024, 256, 0, stream>>>(W_out1, 512, 512, Bcat1, 768);
  k_tcast<<<512, 256, 0, stream>>>(W_self1, 256, 512, Bcat1 + 512, 768);
  k_tcast<<<512, 256, 0, stream>>>(W_in2, 512, 256, Win2t, 512);
  k_tcast<<<256, 256, 0, stream>>>(W_out2, 256, 256, Bcat2, 768);
  k_tcast<<<512, 256, 0, stream>>>(W_self2, 512, 256, Bcat2 + 256, 768);

  // layer 1 (all grids = 512 blocks = 2 blocks/CU)
  k_gemm_bias_w<<<dim3(64, 8), 256, 0, stream>>>(Win1t, Acat1 + 512, 256, 256, 768,
                                                 T1t, NN, b_in1);
  k_gemm_agg_w<<<dim3(4, 128), 256, 0, stream>>>(Mt, T1t, NN, NN, NN,
                                                 Acat1, 768, colsum, colmax, T1t);
  k_gemm_out_w<<<dim3(4, 128), 256, 0, stream>>>(Acat1, Bcat1, 768, 768, 768,
                                                 C2, 512, b_out1, b_self1);
  k_ln_relu_bf16<<<8192, 256, 0, stream>>>(C2, 512, g1, be1, Acat2 + 256, 768);

  // layer 2 (same W^T = Mt, colsum, colmax)
  k_gemm_bias_n<<<dim3(128, 4), 256, 0, stream>>>(Win2t, Acat2 + 256, 512, 512, 768,
                                                  T2t, NN, b_in2);
  k_gemm_agg_n<<<dim3(4, 128), 256, 0, stream>>>(Mt, T2t, NN, NN, NN,
                                                 Acat2, 768, colsum, colmax, T2t);
  k_gemm_out_n<<<dim3(4, 128), 256, 0, stream>>>(Acat2, Bcat2, 768, 768, 768,
                                                 C2, 256, b_out2, b_self2);
  k_ln_relu_f32<<<8192, 256, 0, stream>>>(C2, 256, g2, be2, (float*)d_out, 256);
}

// Round 7
// 399.789 us; speedup vs baseline: 2.4308x; 1.1185x over previous
//
#include <hip/hip_runtime.h>
#include <stdint.h>

typedef short bf16x8 __attribute__((ext_vector_type(8)));
typedef short s16x4 __attribute__((ext_vector_type(4)));
typedef float f32x4 __attribute__((ext_vector_type(4)));
typedef unsigned int u32;

#define EPS_A 1e-8f
#define THR_A 1e-6f
#define NN 8192

static __device__ __forceinline__ short f2bf(float f) {
  u32 u = __float_as_uint(f);
  u = u + 0x7FFFu + ((u >> 16) & 1u);   // RNE, no NaN inputs here
  return (short)(u >> 16);
}
static __device__ __forceinline__ float bf2f(short s) {
  return __uint_as_float(((u32)(unsigned short)s) << 16);
}

// ---- P1: single pass over M: transpose-cast -> Mt bf16 [i][j], colsum, colmax
__global__ __launch_bounds__(256) void k_prep_mt(
    const float* __restrict__ M, short* __restrict__ Mt,
    float* __restrict__ colsum, u32* __restrict__ colmax)
{
  __shared__ __align__(16) short tile[256 * 66];  // [i_local][j_local], stride 66
  const int t = threadIdx.x;
  const int i0 = blockIdx.x * 256;
  const int j0 = blockIdx.y * 64;
  const int i = i0 + t;
  float s = 0.f, mx = 0.f;
  #pragma unroll 4
  for (int jj = 0; jj < 64; ++jj) {
    float v = M[(size_t)(j0 + jj) * NN + i];    // coalesced: t -> i
    s += v;
    mx = fmaxf(mx, v);
    tile[t * 66 + jj] = f2bf(v);
  }
  atomicAdd(&colsum[i], s);
  atomicMax(&colmax[i], __float_as_uint(mx));   // M >= 0, uint order == float order
  __syncthreads();
  #pragma unroll
  for (int p = 0; p < 8; ++p) {
    const int r = p * 32 + (t >> 3);
    const int c = t & 7;
    const u32* src = (const u32*)((const char*)tile + r * 132 + c * 16);
    int4 w = make_int4(src[0], src[1], src[2], src[3]);
    *(int4*)((char*)Mt + (((size_t)(i0 + r) * NN + j0) * 2 + c * 16)) = w;
  }
}

// ---- cast node_features fp32 -> bf16 into Acat1 cols 512:768 (ld 768)
__global__ __launch_bounds__(256) void k_cast_nf(const float* __restrict__ nf,
                                                 short* __restrict__ acat) {
  const int idx = blockIdx.x * 256 + threadIdx.x;
  const float4 v = ((const float4*)nf)[idx];
  const int i = idx >> 6;
  const int c = (idx & 63) * 4;
  s16x4 o;
  o.x = f2bf(v.x); o.y = f2bf(v.y); o.z = f2bf(v.z); o.w = f2bf(v.w);
  *(s16x4*)&acat[(size_t)i * 768 + 512 + c] = o;
}

// ---- generic small transpose-cast: out[c*ldo + r] = bf16(in[r*C + c])
__global__ __launch_bounds__(256) void k_tcast(const float* __restrict__ in, int R, int C,
                                               short* __restrict__ out, int ldo) {
  const int idx = blockIdx.x * 256 + threadIdx.x;
  if (idx >= R * C) return;
  const int r = idx / C, c = idx % C;
  out[(size_t)c * ldo + r] = f2bf(in[idx]);
}

// ---- uniform GEMM: C[M,N] = A[M,K] @ B[N,K]^T, bf16 in, fp32 acc
// 64 x BN tile, BK=32, round-6 skeleton (precomputed pointers, +k0 only),
// padded LDS rows (40 shorts = 80 B), XCD block swizzle per z-slice.
// blockIdx.z = split-K index: A,B advance z*K columns (K = per-split K).
// EPI 0: += bias0[m], bf16 out
// EPI 2: += bias0[n]+bias1[n], fp32 out
// EPI 3: raw bf16 partial -> Cout + z*pstride
template <int BN, int EPI>
__device__ __forceinline__ void gemm_body(
    const short* __restrict__ A, const short* __restrict__ B, int K, int ldA, int ldB,
    void* __restrict__ Cout, int ldC, size_t pstride,
    const float* __restrict__ bias0, const float* __restrict__ bias1)
{
  constexpr int BM = 64;
  constexpr int MI = BM / 32;               // 2
  constexpr int NI = BN / 32;               // 4 (BN=128) or 2 (BN=64)
  constexpr int LDP = 40;                   // padded row stride in shorts (80 B)
  __shared__ __align__(16) short As[BM * LDP];
  __shared__ __align__(16) short Bs[BN * LDP];
  const int t = threadIdx.x;

  // split-K column offset
  const int sk = blockIdx.z;
  A += (size_t)sk * K;
  B += (size_t)sk * K;

  // XCD-aware block swizzle within each z-slice (gx*gy % 8 == 0 for all launches)
  const int gx = gridDim.x;
  int flat = blockIdx.y * gx + blockIdx.x;
  const int cpx = (gx * gridDim.y) >> 3;
  flat = (flat & 7) * cpx + (flat >> 3);
  const int bx = flat % gx, by = flat / gx;
  const int m0 = by * BM, n0 = bx * BN;

  const int wid = t >> 6, l = t & 63;
  const int wr = wid >> 1, wc = wid & 1;    // 2x2 waves, (BM/2) x (BN/2) each
  const int lr = l & 15, lk = l >> 4;

  f32x4 acc[MI][NI] = {};

  const int sr = t >> 2;                    // staging row 0..63
  const int sc = (t & 3) * 8;               // short col 0/8/16/24
  const short* gA0 = A + (size_t)(m0 + sr) * ldA + sc;
  const short* gB0 = B + (size_t)(n0 + sr) * ldB + sc;
  const short* gB1 = gB0 + (size_t)64 * ldB;

  for (int k0 = 0; k0 < K; k0 += 32) {
    const int4 a0 = *(const int4*)(gA0 + k0);
    const int4 b0 = *(const int4*)(gB0 + k0);
    int4 b1 = make_int4(0, 0, 0, 0);
    if (NI == 4) b1 = *(const int4*)(gB1 + k0);
    __syncthreads();                        // protect previous iteration's reads
    *(int4*)&As[sr * LDP + sc] = a0;
    *(int4*)&Bs[sr * LDP + sc] = b0;
    if (NI == 4) *(int4*)&Bs[(64 + sr) * LDP + sc] = b1;
    __syncthreads();

    bf16x8 av[MI], bv[NI];
    #pragma unroll
    for (int mi = 0; mi < MI; ++mi)
      av[mi] = *(const bf16x8*)&As[(wr * (BM / 2) + mi * 16 + lr) * LDP + lk * 8];
    #pragma unroll
    for (int ni = 0; ni < NI; ++ni)
      bv[ni] = *(const bf16x8*)&Bs[(wc * (BN / 2) + ni * 16 + lr) * LDP + lk * 8];
    #pragma unroll
    for (int mi = 0; mi < MI; ++mi)
      #pragma unroll
      for (int ni = 0; ni < NI; ++ni)
        acc[mi][ni] = __builtin_amdgcn_mfma_f32_16x16x32_bf16(av[mi], bv[ni], acc[mi][ni], 0, 0, 0);
  }

  short* outp = (short*)Cout;
  if (EPI == 3) outp += pstride * sk;

  #pragma unroll
  for (int mi = 0; mi < MI; ++mi) {
    #pragma unroll
    for (int r = 0; r < 4; ++r) {
      const int m = m0 + wr * (BM / 2) + mi * 16 + lk * 4 + r;
      float b0 = 0.f;
      if (EPI == 0) b0 = bias0[m];
      #pragma unroll
      for (int ni = 0; ni < NI; ++ni) {
        const int n = n0 + wc * (BN / 2) + ni * 16 + lr;
        float v = acc[mi][ni][r];
        if (EPI == 0) {
          v += b0;
          outp[(size_t)m * ldC + n] = f2bf(v);
        } else if (EPI == 3) {
          outp[(size_t)m * ldC + n] = f2bf(v);
        } else {
          v += bias0[n] + bias1[n];
          ((float*)Cout)[(size_t)m * ldC + n] = v;
        }
      }
    }
  }
}

__global__ __launch_bounds__(256) void k_gemm_bias_w(
    const short* __restrict__ A, const short* __restrict__ B, int K, int ldA, int ldB,
    void* __restrict__ C, int ldC, const float* __restrict__ bias0) {
  gemm_body<128, 0>(A, B, K, ldA, ldB, C, ldC, 0, bias0, nullptr);
}
__global__ __launch_bounds__(256) void k_gemm_bias_n(
    const short* __restrict__ A, const short* __restrict__ B, int K, int ldA, int ldB,
    void* __restrict__ C, int ldC, const float* __restrict__ bias0) {
  gemm_body<64, 0>(A, B, K, ldA, ldB, C, ldC, 0, bias0, nullptr);
}
__global__ __launch_bounds__(256) void k_gemm_sk_w(
    const short* __restrict__ A, const short* __restrict__ B, int K, int ldA, int ldB,
    void* __restrict__ C, int ldC, size_t pstride) {
  gemm_body<128, 3>(A, B, K, ldA, ldB, C, ldC, pstride, nullptr, nullptr);
}
__global__ __launch_bounds__(256) void k_gemm_sk_n(
    const short* __restrict__ A, const short* __restrict__ B, int K, int ldA, int ldB,
    void* __restrict__ C, int ldC, size_t pstride) {
  gemm_body<64, 3>(A, B, K, ldA, ldB, C, ldC, pstride, nullptr, nullptr);
}
__global__ __launch_bounds__(256) void k_gemm_out_w(
    const short* __restrict__ A, const short* __restrict__ B, int K, int ldA, int ldB,
    void* __restrict__ C, int ldC, const float* __restrict__ bias0,
    const float* __restrict__ bias1) {
  gemm_body<128, 2>(A, B, K, ldA, ldB, C, ldC, 0, bias0, bias1);
}
__global__ __launch_bounds__(256) void k_gemm_out_n(
    const short* __restrict__ A, const short* __restrict__ B, int K, int ldA, int ldB,
    void* __restrict__ C, int ldC, const float* __restrict__ bias0,
    const float* __restrict__ bias1) {
  gemm_body<64, 2>(A, B, K, ldA, ldB, C, ldC, 0, bias0, bias1);
}

// ---- split-K reduce + agg epilogue: sum 4 bf16 partials, normalize, fallback, bf16 out
__global__ __launch_bounds__(256) void k_sk_reduce4(
    const short* __restrict__ P, int N, size_t pstride,
    const float* __restrict__ colsum, const u32* __restrict__ colmax,
    const short* __restrict__ Tfall, short* __restrict__ out, int ldo)
{
  const int idx = blockIdx.x * 256 + threadIdx.x;   // one s16x4 per thread
  const int nq = N >> 2;
  const int m = idx / nq;
  const int c4 = (idx - m * nq) * 4;
  const size_t base = (size_t)m * N + c4;
  float a0 = 0.f, a1 = 0.f, a2 = 0.f, a3 = 0.f;
  #pragma unroll
  for (int s = 0; s < 4; ++s) {
    s16x4 v = *(const s16x4*)&P[pstride * s + base];
    a0 += bf2f(v.x); a1 += bf2f(v.y); a2 += bf2f(v.z); a3 += bf2f(v.w);
  }
  const float cs = colsum[m];
  const float rc = 1.f / (cs + EPS_A);
  const float wsum = cs * rc;
  const float rcw = rc / (wsum + EPS_A);
  const bool he = __uint_as_float(colmax[m]) * rc > THR_A;
  a0 *= rcw; a1 *= rcw; a2 *= rcw; a3 *= rcw;
  if (__ballot(!he)) {                     // fallback is rare: wave-uniform skip
    if (!he) {
      a0 = bf2f(Tfall[(size_t)(c4 + 0) * NN + m]);
      a1 = bf2f(Tfall[(size_t)(c4 + 1) * NN + m]);
      a2 = bf2f(Tfall[(size_t)(c4 + 2) * NN + m]);
      a3 = bf2f(Tfall[(size_t)(c4 + 3) * NN + m]);
    }
  }
  s16x4 o;
  o.x = f2bf(a0); o.y = f2bf(a1); o.z = f2bf(a2); o.w = f2bf(a3);
  *(s16x4*)&out[(size_t)m * ldo + c4] = o;
}

// ---- row LayerNorm + ReLU, fp32 in.  MODE 0: bf16 out (ld-strided), MODE 1: fp32 out
template <int MODE>
__device__ __forceinline__ void ln_relu_body(
    const float* __restrict__ X, int W,
    const float* __restrict__ g, const float* __restrict__ be,
    void* __restrict__ out, int ldo)
{
  const int row = blockIdx.x;
  const int t = threadIdx.x;
  const float* x = X + (size_t)row * W;
  float v0 = x[t], v1 = 0.f;
  float s = v0, ss = v0 * v0;
  if (W == 512) { v1 = x[t + 256]; s += v1; ss += v1 * v1; }
  #pragma unroll
  for (int off = 32; off; off >>= 1) {
    s += __shfl_down(s, off);
    ss += __shfl_down(ss, off);
  }
  __shared__ float red[8];
  const int wid = t >> 6;
  if ((t & 63) == 0) { red[wid] = s; red[4 + wid] = ss; }
  __syncthreads();
  s = red[0] + red[1] + red[2] + red[3];
  ss = red[4] + red[5] + red[6] + red[7];
  const float mu = s / W;
  const float var = ss / W - mu * mu;
  const float sc = rsqrtf(var + 1e-5f);
  float y = fmaxf((v0 - mu) * sc * g[t] + be[t], 0.f);
  if (MODE == 0) ((short*)out)[(size_t)row * ldo + t] = f2bf(y);
  else           ((float*)out)[(size_t)row * ldo + t] = y;
  if (W == 512) {
    float y1 = fmaxf((v1 - mu) * sc * g[t + 256] + be[t + 256], 0.f);
    if (MODE == 0) ((short*)out)[(size_t)row * ldo + t + 256] = f2bf(y1);
    else           ((float*)out)[(size_t)row * ldo + t + 256] = y1;
  }
}

__global__ __launch_bounds__(256) void k_ln_relu_bf16(
    const float* __restrict__ X, int W, const float* __restrict__ g,
    const float* __restrict__ be, short* __restrict__ out, int ldo) {
  ln_relu_body<0>(X, W, g, be, out, ldo);
}
__global__ __launch_bounds__(256) void k_ln_relu_f32(
    const float* __restrict__ X, int W, const float* __restrict__ g,
    const float* __restrict__ be, float* __restrict__ out, int ldo) {
  ln_relu_body<1>(X, W, g, be, out, ldo);
}

extern "C" void kernel_launch(void* const* d_in, const int* in_sizes, int n_in,
                              void* d_out, int out_size, void* d_ws, size_t ws_size,
                              hipStream_t stream) {
  const float* nf      = (const float*)d_in[0];
  const float* Mob     = (const float*)d_in[1];
  const float* W_in1   = (const float*)d_in[2];
  const float* b_in1   = (const float*)d_in[3];
  const float* W_out1  = (const float*)d_in[4];
  const float* b_out1  = (const float*)d_in[5];
  const float* W_self1 = (const float*)d_in[6];
  const float* b_self1 = (const float*)d_in[7];
  const float* g1      = (const float*)d_in[8];
  const float* be1     = (const float*)d_in[9];
  const float* W_in2   = (const float*)d_in[10];
  const float* b_in2   = (const float*)d_in[11];
  const float* W_out2  = (const float*)d_in[12];
  const float* b_out2  = (const float*)d_in[13];
  const float* W_self2 = (const float*)d_in[14];
  const float* b_self2 = (const float*)d_in[15];
  const float* g2      = (const float*)d_in[16];
  const float* be2     = (const float*)d_in[17];

  char* ws = (char*)d_ws;
  float* colsum = (float*)(ws);                       // 8192 f32
  u32*   colmax = (u32*)(ws + 32768);                 // 8192 u32
  short* Mt     = (short*)(ws + 65536);               // [8192][8192] bf16 (unnormalized W^T)
  short* Acat1  = (short*)(ws + 134283264);           // [8192][768]: [agg1(512) | nf(256)]
  short* T1t    = (short*)(ws + 146866176);           // [512][8192]
  float* C2     = (float*)(ws + 155254784);           // [8192][512] f32 (reused [8192][256])
  short* Acat2  = (short*)(ws + 172032000);           // [8192][768]: [agg2(256) | h1(512)]
  short* T2t    = (short*)(ws + 184614912);           // [256][8192]
  short* Bcat1  = (short*)(ws + 188809216);           // [512][768]: [Wout1^T | Wself1^T]
  short* Bcat2  = (short*)(ws + 189595648);           // [256][768]: [Wout2^T | Wself2^T]
  short* Win1t  = (short*)(ws + 189988864);           // [512][256]
  short* Win2t  = (short*)(ws + 190251008);           // [256][512]
  // split-K bf16 partials (overlap dead regions; schedule verified):
  short* P1     = (short*)(ws + 155254784);           // 4 x [8192][512] bf16 = 32 MB (C2+Acat2+T2t)
  short* P2     = (short*)(ws + 146866176);           // 4 x [8192][256] bf16 = 16 MB (T1t+C2 front)

  hipMemsetAsync(ws, 0, 65536, stream);  // zero colsum + colmax every call

  k_prep_mt<<<dim3(32, 128), 256, 0, stream>>>(Mob, Mt, colsum, colmax);
  k_cast_nf<<<2048, 256, 0, stream>>>(nf, Acat1);
  k_tcast<<<512, 256, 0, stream>>>(W_in1, 256, 512, Win1t, 256);
  k_tcast<<<1024, 256, 0, stream>>>(W_out1, 512, 512, Bcat1, 768);
  k_tcast<<<512, 256, 0, stream>>>(W_self1, 256, 512, Bcat1 + 512, 768);
  k_tcast<<<512, 256, 0, stream>>>(W_in2, 512, 256, Win2t, 512);
  k_tcast<<<256, 256, 0, stream>>>(W_out2, 256, 256, Bcat2, 768);
  k_tcast<<<512, 256, 0, stream>>>(W_self2, 512, 256, Bcat2 + 256, 768);

  // layer 1
  k_gemm_bias_w<<<dim3(64, 8), 256, 0, stream>>>(Win1t, Acat1 + 512, 256, 256, 768,
                                                 T1t, NN, b_in1);
  k_gemm_sk_w<<<dim3(4, 128, 4), 256, 0, stream>>>(Mt, T1t, 2048, NN, NN,
                                                   P1, 512, (size_t)8192 * 512);
  k_sk_reduce4<<<4096, 256, 0, stream>>>(P1, 512, (size_t)8192 * 512,
                                         colsum, colmax, T1t, Acat1, 768);
  k_gemm_out_w<<<dim3(4, 128), 256, 0, stream>>>(Acat1, Bcat1, 768, 768, 768,
                                                 C2, 512, b_out1, b_self1);
  k_ln_relu_bf16<<<8192, 256, 0, stream>>>(C2, 512, g1, be1, Acat2 + 256, 768);

  // layer 2 (same W^T = Mt, colsum, colmax)
  k_gemm_bias_n<<<dim3(128, 4), 256, 0, stream>>>(Win2t, Acat2 + 256, 512, 512, 768,
                                                  T2t, NN, b_in2);
  k_gemm_sk_n<<<dim3(4, 128, 4), 256, 0, stream>>>(Mt, T2t, 2048, NN, NN,
                                                   P2, 256, (size_t)8192 * 256);
  k_sk_reduce4<<<2048, 256, 0, stream>>>(P2, 256, (size_t)8192 * 256,
                                         colsum, colmax, T2t, Acat2, 768);
  k_gemm_out_n<<<dim3(4, 128), 256, 0, stream>>>(Acat2, Bcat2, 768, 768, 768,
                                                 C2, 256, b_out2, b_self2);
  k_ln_relu_f32<<<8192, 256, 0, stream>>>(C2, 256, g2, be2, (float*)d_out, 256);
}

// Round 9
// 375.207 us; speedup vs baseline: 2.5901x; 1.0655x over previous
//
#include <hip/hip_runtime.h>
#include <stdint.h>

typedef short bf16x8 __attribute__((ext_vector_type(8)));
typedef short s16x4 __attribute__((ext_vector_type(4)));
typedef float f32x4 __attribute__((ext_vector_type(4)));
typedef unsigned int u32;

#define EPS_A 1e-8f
#define THR_A 1e-6f
#define NN 8192

static __device__ __forceinline__ short f2bf(float f) {
  u32 u = __float_as_uint(f);
  u = u + 0x7FFFu + ((u >> 16) & 1u);   // RNE, no NaN inputs here
  return (short)(u >> 16);
}
static __device__ __forceinline__ float bf2f(short s) {
  return __uint_as_float(((u32)(unsigned short)s) << 16);
}
// conflict-free LDS offset (shorts): row stride 32 shorts (64B); XOR the 16B-slot
// index (bits 3..5) with the 128B-line index -> write/A-read/B-read all min-phase
static __device__ __forceinline__ int swz(int row, int slot8) {
  int off = row * 32 + slot8 * 8;
  return off ^ (((row >> 1) & 7) << 3);
}

// ---- P1: single pass over M: transpose-cast -> Mt bf16 [i][j], colsum, colmax
__global__ __launch_bounds__(256) void k_prep_mt(
    const float* __restrict__ M, short* __restrict__ Mt,
    float* __restrict__ colsum, u32* __restrict__ colmax)
{
  __shared__ __align__(16) short tile[256 * 66];  // [i_local][j_local], stride 66
  const int t = threadIdx.x;
  const int i0 = blockIdx.x * 256;
  const int j0 = blockIdx.y * 64;
  const int i = i0 + t;
  float s = 0.f, mx = 0.f;
  #pragma unroll 4
  for (int jj = 0; jj < 64; ++jj) {
    float v = M[(size_t)(j0 + jj) * NN + i];    // coalesced: t -> i
    s += v;
    mx = fmaxf(mx, v);
    tile[t * 66 + jj] = f2bf(v);
  }
  atomicAdd(&colsum[i], s);
  atomicMax(&colmax[i], __float_as_uint(mx));   // M >= 0, uint order == float order
  __syncthreads();
  #pragma unroll
  for (int p = 0; p < 8; ++p) {
    const int r = p * 32 + (t >> 3);
    const int c = t & 7;
    const u32* src = (const u32*)((const char*)tile + r * 132 + c * 16);
    int4 w = make_int4(src[0], src[1], src[2], src[3]);
    *(int4*)((char*)Mt + (((size_t)(i0 + r) * NN + j0) * 2 + c * 16)) = w;
  }
}

// ---- cast node_features fp32 -> bf16 into Acat1 cols 512:768 (ld 768)
__global__ __launch_bounds__(256) void k_cast_nf(const float* __restrict__ nf,
                                                 short* __restrict__ acat) {
  const int idx = blockIdx.x * 256 + threadIdx.x;
  const float4 v = ((const float4*)nf)[idx];
  const int i = idx >> 6;
  const int c = (idx & 63) * 4;
  s16x4 o;
  o.x = f2bf(v.x); o.y = f2bf(v.y); o.z = f2bf(v.z); o.w = f2bf(v.w);
  *(s16x4*)&acat[(size_t)i * 768 + 512 + c] = o;
}

// ---- generic small transpose-cast: out[c*ldo + r] = bf16(in[r*C + c])
__global__ __launch_bounds__(256) void k_tcast(const float* __restrict__ in, int R, int C,
                                               short* __restrict__ out, int ldo) {
  const int idx = blockIdx.x * 256 + threadIdx.x;
  if (idx >= R * C) return;
  const int r = idx / C, c = idx % C;
  out[(size_t)c * ldo + r] = f2bf(in[idx]);
}

// ---- 64 x BN GEMM (round-6/7 proven body): bias / out epilogues
template <int BN, int EPI>
__device__ __forceinline__ void gemm_body(
    const short* __restrict__ A, const short* __restrict__ B, int K, int ldA, int ldB,
    void* __restrict__ Cout, int ldC,
    const float* __restrict__ bias0, const float* __restrict__ bias1)
{
  constexpr int BM = 64;
  constexpr int MI = BM / 32;               // 2
  constexpr int NI = BN / 32;               // 4 (BN=128) or 2 (BN=64)
  constexpr int LDP = 40;                   // padded row stride in shorts (80 B)
  __shared__ __align__(16) short As[BM * LDP];
  __shared__ __align__(16) short Bs[BN * LDP];
  const int t = threadIdx.x;

  const int gx = gridDim.x;
  int flat = blockIdx.y * gx + blockIdx.x;
  const int cpx = (gx * gridDim.y) >> 3;
  flat = (flat & 7) * cpx + (flat >> 3);
  const int bx = flat % gx, by = flat / gx;
  const int m0 = by * BM, n0 = bx * BN;

  const int wid = t >> 6, l = t & 63;
  const int wr = wid >> 1, wc = wid & 1;    // 2x2 waves, (BM/2) x (BN/2) each
  const int lr = l & 15, lk = l >> 4;

  f32x4 acc[MI][NI] = {};

  const int sr = t >> 2;                    // staging row 0..63
  const int sc = (t & 3) * 8;               // short col 0/8/16/24
  const short* gA0 = A + (size_t)(m0 + sr) * ldA + sc;
  const short* gB0 = B + (size_t)(n0 + sr) * ldB + sc;
  const short* gB1 = gB0 + (size_t)64 * ldB;

  for (int k0 = 0; k0 < K; k0 += 32) {
    const int4 a0 = *(const int4*)(gA0 + k0);
    const int4 b0 = *(const int4*)(gB0 + k0);
    int4 b1 = make_int4(0, 0, 0, 0);
    if (NI == 4) b1 = *(const int4*)(gB1 + k0);
    __syncthreads();                        // protect previous iteration's reads
    *(int4*)&As[sr * LDP + sc] = a0;
    *(int4*)&Bs[sr * LDP + sc] = b0;
    if (NI == 4) *(int4*)&Bs[(64 + sr) * LDP + sc] = b1;
    __syncthreads();

    bf16x8 av[MI], bv[NI];
    #pragma unroll
    for (int mi = 0; mi < MI; ++mi)
      av[mi] = *(const bf16x8*)&As[(wr * (BM / 2) + mi * 16 + lr) * LDP + lk * 8];
    #pragma unroll
    for (int ni = 0; ni < NI; ++ni)
      bv[ni] = *(const bf16x8*)&Bs[(wc * (BN / 2) + ni * 16 + lr) * LDP + lk * 8];
    #pragma unroll
    for (int mi = 0; mi < MI; ++mi)
      #pragma unroll
      for (int ni = 0; ni < NI; ++ni)
        acc[mi][ni] = __builtin_amdgcn_mfma_f32_16x16x32_bf16(av[mi], bv[ni], acc[mi][ni], 0, 0, 0);
  }

  #pragma unroll
  for (int mi = 0; mi < MI; ++mi) {
    #pragma unroll
    for (int r = 0; r < 4; ++r) {
      const int m = m0 + wr * (BM / 2) + mi * 16 + lk * 4 + r;
      float b0 = 0.f;
      if (EPI == 0) b0 = bias0[m];
      #pragma unroll
      for (int ni = 0; ni < NI; ++ni) {
        const int n = n0 + wc * (BN / 2) + ni * 16 + lr;
        float v = acc[mi][ni][r];
        if (EPI == 0) {
          v += b0;
          ((short*)Cout)[(size_t)m * ldC + n] = f2bf(v);
        } else {
          v += bias0[n] + bias1[n];
          ((float*)Cout)[(size_t)m * ldC + n] = v;
        }
      }
    }
  }
}

__global__ __launch_bounds__(256) void k_gemm_bias_w(
    const short* __restrict__ A, const short* __restrict__ B, int K, int ldA, int ldB,
    void* __restrict__ C, int ldC, const float* __restrict__ bias0) {
  gemm_body<128, 0>(A, B, K, ldA, ldB, C, ldC, bias0, nullptr);
}
__global__ __launch_bounds__(256) void k_gemm_bias_n(
    const short* __restrict__ A, const short* __restrict__ B, int K, int ldA, int ldB,
    void* __restrict__ C, int ldC, const float* __restrict__ bias0) {
  gemm_body<64, 0>(A, B, K, ldA, ldB, C, ldC, bias0, nullptr);
}
__global__ __launch_bounds__(256) void k_gemm_out_w(
    const short* __restrict__ A, const short* __restrict__ B, int K, int ldA, int ldB,
    void* __restrict__ C, int ldC, const float* __restrict__ bias0,
    const float* __restrict__ bias1) {
  gemm_body<128, 2>(A, B, K, ldA, ldB, C, ldC, bias0, bias1);
}
__global__ __launch_bounds__(256) void k_gemm_out_n(
    const short* __restrict__ A, const short* __restrict__ B, int K, int ldA, int ldB,
    void* __restrict__ C, int ldC, const float* __restrict__ bias0,
    const float* __restrict__ bias1) {
  gemm_body<64, 2>(A, B, K, ldA, ldB, C, ldC, bias0, bias1);
}

// ---- 128x128 split-K GEMM, BK=32, conflict-free XOR-swizzled LDS.
// 16 MFMA per 10 LDS-ops per wave-iter (vs 8 per 9 in the 64-tile body).
// blockIdx.z = split index; raw bf16 partial -> P + z*pstride.
__global__ __launch_bounds__(256) void k_gemm_sk128(
    const short* __restrict__ A, const short* __restrict__ B, int K, int ldA, int ldB,
    short* __restrict__ P, int ldC, size_t pstride)
{
  __shared__ __align__(16) short As[128 * 32];
  __shared__ __align__(16) short Bs[128 * 32];
  const int t = threadIdx.x;

  const int sk = blockIdx.z;
  A += (size_t)sk * K;
  B += (size_t)sk * K;

  const int gx = gridDim.x;
  int flat = blockIdx.y * gx + blockIdx.x;
  const int cpx = (gx * gridDim.y) >> 3;
  flat = (flat & 7) * cpx + (flat >> 3);
  const int bx = flat % gx, by = flat / gx;
  const int m0 = by * 128, n0 = bx * 128;

  const int wid = t >> 6, l = t & 63;
  const int wr = wid >> 1, wc = wid & 1;    // 2x2 waves, 64x64 each
  const int lr = l & 15, lk = l >> 4;

  f32x4 acc[4][4] = {};

  const int sr = t >> 2;                    // staging row 0..63 (and +64)
  const int sq = t & 3;                     // 16B slot 0..3
  const short* gA0 = A + (size_t)(m0 + sr) * ldA + sq * 8;
  const short* gA1 = gA0 + (size_t)64 * ldA;
  const short* gB0 = B + (size_t)(n0 + sr) * ldB + sq * 8;
  const short* gB1 = gB0 + (size_t)64 * ldB;
  const int w0 = swz(sr, sq), w1 = swz(sr + 64, sq);

  for (int k0 = 0; k0 < K; k0 += 32) {
    const int4 a0 = *(const int4*)(gA0 + k0);
    const int4 a1 = *(const int4*)(gA1 + k0);
    const int4 b0 = *(const int4*)(gB0 + k0);
    const int4 b1 = *(const int4*)(gB1 + k0);
    __syncthreads();                        // protect previous iteration's reads
    *(int4*)&As[w0] = a0;
    *(int4*)&As[w1] = a1;
    *(int4*)&Bs[w0] = b0;
    *(int4*)&Bs[w1] = b1;
    __syncthreads();

    bf16x8 av[4], bv[4];
    #pragma unroll
    for (int mi = 0; mi < 4; ++mi)
      av[mi] = *(const bf16x8*)&As[swz(wr * 64 + mi * 16 + lr, lk)];
    #pragma unroll
    for (int ni = 0; ni < 4; ++ni)
      bv[ni] = *(const bf16x8*)&Bs[swz(wc * 64 + ni * 16 + lr, lk)];
    #pragma unroll
    for (int mi = 0; mi < 4; ++mi)
      #pragma unroll
      for (int ni = 0; ni < 4; ++ni)
        acc[mi][ni] = __builtin_amdgcn_mfma_f32_16x16x32_bf16(av[mi], bv[ni], acc[mi][ni], 0, 0, 0);
  }

  short* outp = P + pstride * sk;
  #pragma unroll
  for (int mi = 0; mi < 4; ++mi) {
    #pragma unroll
    for (int r = 0; r < 4; ++r) {
      const int m = m0 + wr * 64 + mi * 16 + lk * 4 + r;
      #pragma unroll
      for (int ni = 0; ni < 4; ++ni) {
        const int n = n0 + wc * 64 + ni * 16 + lr;
        outp[(size_t)m * ldC + n] = f2bf(acc[mi][ni][r]);
      }
    }
  }
}

// ---- split-K reduce + agg epilogue: sum S bf16 partials, normalize, fallback
__global__ __launch_bounds__(256) void k_sk_reduce(
    const short* __restrict__ P, int N, size_t pstride, int S,
    const float* __restrict__ colsum, const u32* __restrict__ colmax,
    const short* __restrict__ Tfall, short* __restrict__ out, int ldo)
{
  const int idx = blockIdx.x * 256 + threadIdx.x;   // one s16x4 per thread
  const int nq = N >> 2;
  const int m = idx / nq;
  const int c4 = (idx - m * nq) * 4;
  const size_t base = (size_t)m * N + c4;
  float a0 = 0.f, a1 = 0.f, a2 = 0.f, a3 = 0.f;
  for (int s = 0; s < S; ++s) {
    s16x4 v = *(const s16x4*)&P[pstride * s + base];
    a0 += bf2f(v.x); a1 += bf2f(v.y); a2 += bf2f(v.z); a3 += bf2f(v.w);
  }
  const float cs = colsum[m];
  const float rc = 1.f / (cs + EPS_A);
  const float wsum = cs * rc;
  const float rcw = rc / (wsum + EPS_A);
  const bool he = __uint_as_float(colmax[m]) * rc > THR_A;
  a0 *= rcw; a1 *= rcw; a2 *= rcw; a3 *= rcw;
  if (__ballot(!he)) {                     // fallback is rare: wave-uniform skip
    if (!he) {
      a0 = bf2f(Tfall[(size_t)(c4 + 0) * NN + m]);
      a1 = bf2f(Tfall[(size_t)(c4 + 1) * NN + m]);
      a2 = bf2f(Tfall[(size_t)(c4 + 2) * NN + m]);
      a3 = bf2f(Tfall[(size_t)(c4 + 3) * NN + m]);
    }
  }
  s16x4 o;
  o.x = f2bf(a0); o.y = f2bf(a1); o.z = f2bf(a2); o.w = f2bf(a3);
  *(s16x4*)&out[(size_t)m * ldo + c4] = o;
}

// ---- row LayerNorm + ReLU, fp32 in.  MODE 0: bf16 out (ld-strided), MODE 1: fp32 out
template <int MODE>
__device__ __forceinline__ void ln_relu_body(
    const float* __restrict__ X, int W,
    const float* __restrict__ g, const float* __restrict__ be,
    void* __restrict__ out, int ldo)
{
  const int row = blockIdx.x;
  const int t = threadIdx.x;
  const float* x = X + (size_t)row * W;
  float v0 = x[t], v1 = 0.f;
  float s = v0, ss = v0 * v0;
  if (W == 512) { v1 = x[t + 256]; s += v1; ss += v1 * v1; }
  #pragma unroll
  for (int off = 32; off; off >>= 1) {
    s += __shfl_down(s, off);
    ss += __shfl_down(ss, off);
  }
  __shared__ float red[8];
  const int wid = t >> 6;
  if ((t & 63) == 0) { red[wid] = s; red[4 + wid] = ss; }
  __syncthreads();
  s = red[0] + red[1] + red[2] + red[3];
  ss = red[4] + red[5] + red[6] + red[7];
  const float mu = s / W;
  const float var = ss / W - mu * mu;
  const float sc = rsqrtf(var + 1e-5f);
  float y = fmaxf((v0 - mu) * sc * g[t] + be[t], 0.f);
  if (MODE == 0) ((short*)out)[(size_t)row * ldo + t] = f2bf(y);
  else           ((float*)out)[(size_t)row * ldo + t] = y;
  if (W == 512) {
    float y1 = fmaxf((v1 - mu) * sc * g[t + 256] + be[t + 256], 0.f);
    if (MODE == 0) ((short*)out)[(size_t)row * ldo + t + 256] = f2bf(y1);
    else           ((float*)out)[(size_t)row * ldo + t + 256] = y1;
  }
}

__global__ __launch_bounds__(256) void k_ln_relu_bf16(
    const float* __restrict__ X, int W, const float* __restrict__ g,
    const float* __restrict__ be, short* __restrict__ out, int ldo) {
  ln_relu_body<0>(X, W, g, be, out, ldo);
}
__global__ __launch_bounds__(256) void k_ln_relu_f32(
    const float* __restrict__ X, int W, const float* __restrict__ g,
    const float* __restrict__ be, float* __restrict__ out, int ldo) {
  ln_relu_body<1>(X, W, g, be, out, ldo);
}

extern "C" void kernel_launch(void* const* d_in, const int* in_sizes, int n_in,
                              void* d_out, int out_size, void* d_ws, size_t ws_size,
                              hipStream_t stream) {
  const float* nf      = (const float*)d_in[0];
  const float* Mob     = (const float*)d_in[1];
  const float* W_in1   = (const float*)d_in[2];
  const float* b_in1   = (const float*)d_in[3];
  const float* W_out1  = (const float*)d_in[4];
  const float* b_out1  = (const float*)d_in[5];
  const float* W_self1 = (const float*)d_in[6];
  const float* b_self1 = (const float*)d_in[7];
  const float* g1      = (const float*)d_in[8];
  const float* be1     = (const float*)d_in[9];
  const float* W_in2   = (const float*)d_in[10];
  const float* b_in2   = (const float*)d_in[11];
  const float* W_out2  = (const float*)d_in[12];
  const float* b_out2  = (const float*)d_in[13];
  const float* W_self2 = (const float*)d_in[14];
  const float* b_self2 = (const float*)d_in[15];
  const float* g2      = (const float*)d_in[16];
  const float* be2     = (const float*)d_in[17];

  char* ws = (char*)d_ws;
  float* colsum = (float*)(ws);                       // 8192 f32
  u32*   colmax = (u32*)(ws + 32768);                 // 8192 u32
  short* Mt     = (short*)(ws + 65536);               // [8192][8192] bf16 (unnormalized W^T)
  short* Acat1  = (short*)(ws + 134283264);           // [8192][768]: [agg1(512) | nf(256)]
  short* T1t    = (short*)(ws + 146866176);           // [512][8192]
  float* C2     = (float*)(ws + 155254784);           // [8192][512] f32 (reused [8192][256])
  short* Acat2  = (short*)(ws + 172032000);           // [8192][768]: [agg2(256) | h1(512)]
  short* T2t    = (short*)(ws + 184614912);           // [256][8192]
  short* Bcat1  = (short*)(ws + 188809216);           // [512][768]: [Wout1^T | Wself1^T]
  short* Bcat2  = (short*)(ws + 189595648);           // [256][768]: [Wout2^T | Wself2^T]
  short* Win1t  = (short*)(ws + 189988864);           // [512][256]
  short* Win2t  = (short*)(ws + 190251008);           // [256][512]
  // split-K bf16 partials (dead-region overlap; liveness schedule verified):
  // P1: 4 x [8192][512] = 33.5 MB over C2+Acat2+T2t (all dead during sk_w/reduce1)
  short* P1     = (short*)(ws + 155254784);
  // P2: 8 x [8192][256] = 33.5 MB over Acat1+T1t+C2-front (all dead during sk_n/reduce2)
  short* P2     = (short*)(ws + 134283264);

  hipMemsetAsync(ws, 0, 65536, stream);  // zero colsum + colmax every call

  k_prep_mt<<<dim3(32, 128), 256, 0, stream>>>(Mob, Mt, colsum, colmax);
  k_cast_nf<<<2048, 256, 0, stream>>>(nf, Acat1);
  k_tcast<<<512, 256, 0, stream>>>(W_in1, 256, 512, Win1t, 256);
  k_tcast<<<1024, 256, 0, stream>>>(W_out1, 512, 512, Bcat1, 768);
  k_tcast<<<512, 256, 0, stream>>>(W_self1, 256, 512, Bcat1 + 512, 768);
  k_tcast<<<512, 256, 0, stream>>>(W_in2, 512, 256, Win2t, 512);
  k_tcast<<<256, 256, 0, stream>>>(W_out2, 256, 256, Bcat2, 768);
  k_tcast<<<512, 256, 0, stream>>>(W_self2, 512, 256, Bcat2 + 256, 768);

  // layer 1
  k_gemm_bias_w<<<dim3(64, 8), 256, 0, stream>>>(Win1t, Acat1 + 512, 256, 256, 768,
                                                 T1t, NN, b_in1);
  k_gemm_sk128<<<dim3(4, 64, 4), 256, 0, stream>>>(Mt, T1t, 2048, NN, NN,
                                                   P1, 512, (size_t)8192 * 512);
  k_sk_reduce<<<4096, 256, 0, stream>>>(P1, 512, (size_t)8192 * 512, 4,
                                        colsum, colmax, T1t, Acat1, 768);
  k_gemm_out_w<<<dim3(4, 128), 256, 0, stream>>>(Acat1, Bcat1, 768, 768, 768,
                                                 C2, 512, b_out1, b_self1);
  k_ln_relu_bf16<<<8192, 256, 0, stream>>>(C2, 512, g1, be1, Acat2 + 256, 768);

  // layer 2 (same W^T = Mt, colsum, colmax); Acat1/T1t/C2 dead from here
  k_gemm_bias_n<<<dim3(128, 4), 256, 0, stream>>>(Win2t, Acat2 + 256, 512, 512, 768,
                                                  T2t, NN, b_in2);
  k_gemm_sk128<<<dim3(2, 64, 8), 256, 0, stream>>>(Mt, T2t, 1024, NN, NN,
                                                   P2, 256, (size_t)8192 * 256);
  k_sk_reduce<<<2048, 256, 0, stream>>>(P2, 256, (size_t)8192 * 256, 8,
                                        colsum, colmax, T2t, Acat2, 768);
  k_gemm_out_n<<<dim3(4, 128), 256, 0, stream>>>(Acat2, Bcat2, 768, 768, 768,
                                                 C2, 256, b_out2, b_self2);
  k_ln_relu_f32<<<8192, 256, 0, stream>>>(C2, 256, g2, be2, (float*)d_out, 256);
}

// Round 10
// 341.228 us; speedup vs baseline: 2.8480x; 1.0996x over previous
//
#include <hip/hip_runtime.h>
#include <stdint.h>

typedef short bf16x8 __attribute__((ext_vector_type(8)));
typedef short s16x4 __attribute__((ext_vector_type(4)));
typedef float f32x4 __attribute__((ext_vector_type(4)));
typedef unsigned int u32;

#define EPS_A 1e-8f
#define THR_A 1e-6f
#define NN 8192

static __device__ __forceinline__ short f2bf(float f) {
  u32 u = __float_as_uint(f);
  u = u + 0x7FFFu + ((u >> 16) & 1u);   // RNE, no NaN inputs here
  return (short)(u >> 16);
}
static __device__ __forceinline__ float bf2f(short s) {
  return __uint_as_float(((u32)(unsigned short)s) << 16);
}
// conflict-free LDS offset (shorts): row stride 32 shorts (64B); XOR the 16B-slot
// index (bits 3..5) with the 128B-line index -> write/A-read/B-read all min-phase
static __device__ __forceinline__ int swz(int row, int slot8) {
  int off = row * 32 + slot8 * 8;
  return off ^ (((row >> 1) & 7) << 3);
}

// ---- single pass over M: transpose-cast -> Mt bf16 [i][j], colsum, colmax
__global__ __launch_bounds__(256) void k_prep_mt(
    const float* __restrict__ M, short* __restrict__ Mt,
    float* __restrict__ colsum, u32* __restrict__ colmax)
{
  __shared__ __align__(16) short tile[256 * 66];  // [i_local][j_local], stride 66
  const int t = threadIdx.x;
  const int i0 = blockIdx.x * 256;
  const int j0 = blockIdx.y * 64;
  const int i = i0 + t;
  float s = 0.f, mx = 0.f;
  #pragma unroll 4
  for (int jj = 0; jj < 64; ++jj) {
    float v = M[(size_t)(j0 + jj) * NN + i];    // coalesced: t -> i
    s += v;
    mx = fmaxf(mx, v);
    tile[t * 66 + jj] = f2bf(v);
  }
  atomicAdd(&colsum[i], s);
  atomicMax(&colmax[i], __float_as_uint(mx));   // M >= 0, uint order == float order
  __syncthreads();
  #pragma unroll
  for (int p = 0; p < 8; ++p) {
    const int r = p * 32 + (t >> 3);
    const int c = t & 7;
    const u32* src = (const u32*)((const char*)tile + r * 132 + c * 16);
    int4 w = make_int4(src[0], src[1], src[2], src[3]);
    *(int4*)((char*)Mt + (((size_t)(i0 + r) * NN + j0) * 2 + c * 16)) = w;
  }
}

// ---- LDS-tiled transpose-cast fp32->bf16: out[c*R + r] = bf16(in[r*C + c])
__global__ __launch_bounds__(256) void k_trans_cast(
    const float* __restrict__ in, int R, int C, short* __restrict__ out)
{
  __shared__ short tile[64][65];
  const int t = threadIdx.x;
  const int r0 = blockIdx.x * 64, c0 = blockIdx.y * 64;
  #pragma unroll
  for (int p = 0; p < 16; ++p) {
    const int rr = p * 4 + (t >> 6), cc = t & 63;
    tile[rr][cc] = f2bf(in[(size_t)(r0 + rr) * C + c0 + cc]);
  }
  __syncthreads();
  #pragma unroll
  for (int q = 0; q < 16; ++q) {
    const int cc = q * 4 + (t >> 6), rr = t & 63;
    out[(size_t)(c0 + cc) * R + r0 + rr] = tile[rr][cc];
  }
}

// ---- cast node_features fp32 -> bf16 into A1cat cols 256:512 (ld 512)
__global__ __launch_bounds__(256) void k_cast_nf(const float* __restrict__ nf,
                                                 short* __restrict__ a1cat) {
  const int idx = blockIdx.x * 256 + threadIdx.x;   // 524288 quads
  const float4 v = ((const float4*)nf)[idx];
  const int i = idx >> 6;
  const int c = (idx & 63) * 4;
  s16x4 o;
  o.x = f2bf(v.x); o.y = f2bf(v.y); o.z = f2bf(v.z); o.w = f2bf(v.w);
  *(s16x4*)&a1cat[(size_t)i * 512 + 256 + c] = o;
}

// ---- straight fp32 -> bf16 cast (quads)
__global__ __launch_bounds__(256) void k_cast4(const float* __restrict__ in,
                                               short* __restrict__ out) {
  const int idx = blockIdx.x * 256 + threadIdx.x;
  const float4 v = ((const float4*)in)[idx];
  s16x4 o;
  o.x = f2bf(v.x); o.y = f2bf(v.y); o.z = f2bf(v.z); o.w = f2bf(v.w);
  *(s16x4*)&out[idx * 4] = o;
}

// ---- generic small transpose-cast (scattered writes; weights only)
__global__ __launch_bounds__(256) void k_tcast(const float* __restrict__ in, int R, int C,
                                               short* __restrict__ out, int ldo) {
  const int idx = blockIdx.x * 256 + threadIdx.x;
  if (idx >= R * C) return;
  const int r = idx / C, c = idx % C;
  out[(size_t)c * ldo + r] = f2bf(in[idx]);
}

// ---- bias1c[n] = sum_p b_in[p]*W_out[p*512+n] + b_out[n] + b_self[n]  (N=512,P=512)
__global__ __launch_bounds__(256) void k_bias1(
    const float* __restrict__ b_in, const float* __restrict__ W_out,
    const float* __restrict__ b_out, const float* __restrict__ b_self,
    float* __restrict__ outb) {
  const int n = blockIdx.x * 256 + threadIdx.x;
  float a = b_out[n] + b_self[n];
  for (int p = 0; p < 512; ++p) a += b_in[p] * W_out[(size_t)p * 512 + n];
  outb[n] = a;
}
__global__ __launch_bounds__(256) void k_addb(const float* __restrict__ a,
                                              const float* __restrict__ b,
                                              float* __restrict__ o) {
  const int i = threadIdx.x;   // n=256
  o[i] = a[i] + b[i];
}

// ---- 64 x BN GEMM (proven body): EPI 0 += bias0[m] bf16; EPI 2 += bias0[n] fp32;
//      EPI 3 raw bf16
template <int BN, int EPI>
__device__ __forceinline__ void gemm_body(
    const short* __restrict__ A, const short* __restrict__ B, int K, int ldA, int ldB,
    void* __restrict__ Cout, int ldC, const float* __restrict__ bias0)
{
  constexpr int BM = 64;
  constexpr int MI = BM / 32;               // 2
  constexpr int NI = BN / 32;               // 4 (BN=128) or 2 (BN=64)
  constexpr int LDP = 40;                   // padded row stride in shorts (80 B)
  __shared__ __align__(16) short As[BM * LDP];
  __shared__ __align__(16) short Bs[BN * LDP];
  const int t = threadIdx.x;

  const int gx = gridDim.x;
  int flat = blockIdx.y * gx + blockIdx.x;
  const int cpx = (gx * gridDim.y) >> 3;
  flat = (flat & 7) * cpx + (flat >> 3);
  const int bx = flat % gx, by = flat / gx;
  const int m0 = by * BM, n0 = bx * BN;

  const int wid = t >> 6, l = t & 63;
  const int wr = wid >> 1, wc = wid & 1;
  const int lr = l & 15, lk = l >> 4;

  f32x4 acc[MI][NI] = {};

  const int sr = t >> 2;
  const int sc = (t & 3) * 8;
  const short* gA0 = A + (size_t)(m0 + sr) * ldA + sc;
  const short* gB0 = B + (size_t)(n0 + sr) * ldB + sc;
  const short* gB1 = gB0 + (size_t)64 * ldB;

  for (int k0 = 0; k0 < K; k0 += 32) {
    const int4 a0 = *(const int4*)(gA0 + k0);
    const int4 b0 = *(const int4*)(gB0 + k0);
    int4 b1 = make_int4(0, 0, 0, 0);
    if (NI == 4) b1 = *(const int4*)(gB1 + k0);
    __syncthreads();
    *(int4*)&As[sr * LDP + sc] = a0;
    *(int4*)&Bs[sr * LDP + sc] = b0;
    if (NI == 4) *(int4*)&Bs[(64 + sr) * LDP + sc] = b1;
    __syncthreads();

    bf16x8 av[MI], bv[NI];
    #pragma unroll
    for (int mi = 0; mi < MI; ++mi)
      av[mi] = *(const bf16x8*)&As[(wr * (BM / 2) + mi * 16 + lr) * LDP + lk * 8];
    #pragma unroll
    for (int ni = 0; ni < NI; ++ni)
      bv[ni] = *(const bf16x8*)&Bs[(wc * (BN / 2) + ni * 16 + lr) * LDP + lk * 8];
    #pragma unroll
    for (int mi = 0; mi < MI; ++mi)
      #pragma unroll
      for (int ni = 0; ni < NI; ++ni)
        acc[mi][ni] = __builtin_amdgcn_mfma_f32_16x16x32_bf16(av[mi], bv[ni], acc[mi][ni], 0, 0, 0);
  }

  #pragma unroll
  for (int mi = 0; mi < MI; ++mi) {
    #pragma unroll
    for (int r = 0; r < 4; ++r) {
      const int m = m0 + wr * (BM / 2) + mi * 16 + lk * 4 + r;
      float b0 = 0.f;
      if (EPI == 0) b0 = bias0[m];
      #pragma unroll
      for (int ni = 0; ni < NI; ++ni) {
        const int n = n0 + wc * (BN / 2) + ni * 16 + lr;
        float v = acc[mi][ni][r];
        if (EPI == 0) {
          v += b0;
          ((short*)Cout)[(size_t)m * ldC + n] = f2bf(v);
        } else if (EPI == 3) {
          ((short*)Cout)[(size_t)m * ldC + n] = f2bf(v);
        } else {
          v += bias0[n];
          ((float*)Cout)[(size_t)m * ldC + n] = v;
        }
      }
    }
  }
}

__global__ __launch_bounds__(256) void k_gemm_bias_n(
    const short* __restrict__ A, const short* __restrict__ B, int K, int ldA, int ldB,
    void* __restrict__ C, int ldC, const float* __restrict__ bias0) {
  gemm_body<64, 0>(A, B, K, ldA, ldB, C, ldC, bias0);
}
__global__ __launch_bounds__(256) void k_gemm_raw_n(
    const short* __restrict__ A, const short* __restrict__ B, int K, int ldA, int ldB,
    void* __restrict__ C, int ldC) {
  gemm_body<64, 3>(A, B, K, ldA, ldB, C, ldC, nullptr);
}
__global__ __launch_bounds__(256) void k_gemm_out_w(
    const short* __restrict__ A, const short* __restrict__ B, int K, int ldA, int ldB,
    void* __restrict__ C, int ldC, const float* __restrict__ bias0) {
  gemm_body<128, 2>(A, B, K, ldA, ldB, C, ldC, bias0);
}
__global__ __launch_bounds__(256) void k_gemm_out_n(
    const short* __restrict__ A, const short* __restrict__ B, int K, int ldA, int ldB,
    void* __restrict__ C, int ldC, const float* __restrict__ bias0) {
  gemm_body<64, 2>(A, B, K, ldA, ldB, C, ldC, bias0);
}

// ---- 128x128 split-K GEMM, BK=32, conflict-free XOR-swizzled LDS (proven r9).
__global__ __launch_bounds__(256) void k_gemm_sk128(
    const short* __restrict__ A, const short* __restrict__ B, int K, int ldA, int ldB,
    short* __restrict__ P, int ldC, size_t pstride)
{
  __shared__ __align__(16) short As[128 * 32];
  __shared__ __align__(16) short Bs[128 * 32];
  const int t = threadIdx.x;

  const int sk = blockIdx.z;
  A += (size_t)sk * K;
  B += (size_t)sk * K;

  const int gx = gridDim.x;
  int flat = blockIdx.y * gx + blockIdx.x;
  const int cpx = (gx * gridDim.y) >> 3;
  flat = (flat & 7) * cpx + (flat >> 3);
  const int bx = flat % gx, by = flat / gx;
  const int m0 = by * 128, n0 = bx * 128;

  const int wid = t >> 6, l = t & 63;
  const int wr = wid >> 1, wc = wid & 1;
  const int lr = l & 15, lk = l >> 4;

  f32x4 acc[4][4] = {};

  const int sr = t >> 2;
  const int sq = t & 3;
  const short* gA0 = A + (size_t)(m0 + sr) * ldA + sq * 8;
  const short* gA1 = gA0 + (size_t)64 * ldA;
  const short* gB0 = B + (size_t)(n0 + sr) * ldB + sq * 8;
  const short* gB1 = gB0 + (size_t)64 * ldB;
  const int w0 = swz(sr, sq), w1 = swz(sr + 64, sq);

  for (int k0 = 0; k0 < K; k0 += 32) {
    const int4 a0 = *(const int4*)(gA0 + k0);
    const int4 a1 = *(const int4*)(gA1 + k0);
    const int4 b0 = *(const int4*)(gB0 + k0);
    const int4 b1 = *(const int4*)(gB1 + k0);
    __syncthreads();
    *(int4*)&As[w0] = a0;
    *(int4*)&As[w1] = a1;
    *(int4*)&Bs[w0] = b0;
    *(int4*)&Bs[w1] = b1;
    __syncthreads();

    bf16x8 av[4], bv[4];
    #pragma unroll
    for (int mi = 0; mi < 4; ++mi)
      av[mi] = *(const bf16x8*)&As[swz(wr * 64 + mi * 16 + lr, lk)];
    #pragma unroll
    for (int ni = 0; ni < 4; ++ni)
      bv[ni] = *(const bf16x8*)&Bs[swz(wc * 64 + ni * 16 + lr, lk)];
    #pragma unroll
    for (int mi = 0; mi < 4; ++mi)
      #pragma unroll
      for (int ni = 0; ni < 4; ++ni)
        acc[mi][ni] = __builtin_amdgcn_mfma_f32_16x16x32_bf16(av[mi], bv[ni], acc[mi][ni], 0, 0, 0);
  }

  short* outp = P + pstride * sk;
  #pragma unroll
  for (int mi = 0; mi < 4; ++mi) {
    #pragma unroll
    for (int r = 0; r < 4; ++r) {
      const int m = m0 + wr * 64 + mi * 16 + lk * 4 + r;
      #pragma unroll
      for (int ni = 0; ni < 4; ++ni) {
        const int n = n0 + wc * 64 + ni * 16 + lr;
        outp[(size_t)m * ldC + n] = f2bf(acc[mi][ni][r]);
      }
    }
  }
}

// ---- reduce S partials + normalize; fallback substitutes raw h row (coalesced).
// One wave == one row (N=256) -> `he` is wave-uniform.
__global__ __launch_bounds__(256) void k_sk_reduce_sub(
    const short* __restrict__ P, int N, size_t pstride, int S,
    const float* __restrict__ colsum, const u32* __restrict__ colmax,
    const short* __restrict__ hraw, int ldh,
    short* __restrict__ out, int ldo)
{
  const int idx = blockIdx.x * 256 + threadIdx.x;
  const int nq = N >> 2;
  const int m = idx / nq;
  const int c4 = (idx - m * nq) * 4;
  const size_t base = (size_t)m * N + c4;
  float a0 = 0.f, a1 = 0.f, a2 = 0.f, a3 = 0.f;
  for (int s = 0; s < S; ++s) {
    s16x4 v = *(const s16x4*)&P[pstride * s + base];
    a0 += bf2f(v.x); a1 += bf2f(v.y); a2 += bf2f(v.z); a3 += bf2f(v.w);
  }
  const float cs = colsum[m];
  const float rc = 1.f / (cs + EPS_A);
  const float rcw = rc / (cs * rc + EPS_A);
  const bool he = __uint_as_float(colmax[m]) * rc > THR_A;
  s16x4 o;
  if (he) {
    o.x = f2bf(a0 * rcw); o.y = f2bf(a1 * rcw);
    o.z = f2bf(a2 * rcw); o.w = f2bf(a3 * rcw);
  } else {
    o = *(const s16x4*)&hraw[(size_t)m * ldh + c4];
  }
  *(s16x4*)&out[(size_t)m * ldo + c4] = o;
}

// ---- reduce S partials + normalize; fallback gathers T^T (rare, ballot-skipped)
__global__ __launch_bounds__(256) void k_sk_reduce(
    const short* __restrict__ P, int N, size_t pstride, int S,
    const float* __restrict__ colsum, const u32* __restrict__ colmax,
    const short* __restrict__ Tfall, short* __restrict__ out, int ldo)
{
  const int idx = blockIdx.x * 256 + threadIdx.x;
  const int nq = N >> 2;
  const int m = idx / nq;
  const int c4 = (idx - m * nq) * 4;
  const size_t base = (size_t)m * N + c4;
  float a0 = 0.f, a1 = 0.f, a2 = 0.f, a3 = 0.f;
  for (int s = 0; s < S; ++s) {
    s16x4 v = *(const s16x4*)&P[pstride * s + base];
    a0 += bf2f(v.x); a1 += bf2f(v.y); a2 += bf2f(v.z); a3 += bf2f(v.w);
  }
  const float cs = colsum[m];
  const float rc = 1.f / (cs + EPS_A);
  const float rcw = rc / (cs * rc + EPS_A);
  const bool he = __uint_as_float(colmax[m]) * rc > THR_A;
  a0 *= rcw; a1 *= rcw; a2 *= rcw; a3 *= rcw;
  if (__ballot(!he)) {
    if (!he) {
      a0 = bf2f(Tfall[(size_t)(c4 + 0) * NN + m]);
      a1 = bf2f(Tfall[(size_t)(c4 + 1) * NN + m]);
      a2 = bf2f(Tfall[(size_t)(c4 + 2) * NN + m]);
      a3 = bf2f(Tfall[(size_t)(c4 + 3) * NN + m]);
    }
  }
  s16x4 o;
  o.x = f2bf(a0); o.y = f2bf(a1); o.z = f2bf(a2); o.w = f2bf(a3);
  *(s16x4*)&out[(size_t)m * ldo + c4] = o;
}

// ---- row LayerNorm + ReLU, fp32 in.  MODE 0: bf16 out (ld-strided), MODE 1: fp32 out
template <int MODE>
__device__ __forceinline__ void ln_relu_body(
    const float* __restrict__ X, int W,
    const float* __restrict__ g, const float* __restrict__ be,
    void* __restrict__ out, int ldo)
{
  const int row = blockIdx.x;
  const int t = threadIdx.x;
  const float* x = X + (size_t)row * W;
  float v0 = x[t], v1 = 0.f;
  float s = v0, ss = v0 * v0;
  if (W == 512) { v1 = x[t + 256]; s += v1; ss += v1 * v1; }
  #pragma unroll
  for (int off = 32; off; off >>= 1) {
    s += __shfl_down(s, off);
    ss += __shfl_down(ss, off);
  }
  __shared__ float red[8];
  const int wid = t >> 6;
  if ((t & 63) == 0) { red[wid] = s; red[4 + wid] = ss; }
  __syncthreads();
  s = red[0] + red[1] + red[2] + red[3];
  ss = red[4] + red[5] + red[6] + red[7];
  const float mu = s / W;
  const float var = ss / W - mu * mu;
  const float sc = rsqrtf(var + 1e-5f);
  float y = fmaxf((v0 - mu) * sc * g[t] + be[t], 0.f);
  if (MODE == 0) ((short*)out)[(size_t)row * ldo + t] = f2bf(y);
  else           ((float*)out)[(size_t)row * ldo + t] = y;
  if (W == 512) {
    float y1 = fmaxf((v1 - mu) * sc * g[t + 256] + be[t + 256], 0.f);
    if (MODE == 0) ((short*)out)[(size_t)row * ldo + t + 256] = f2bf(y1);
    else           ((float*)out)[(size_t)row * ldo + t + 256] = y1;
  }
}

__global__ __launch_bounds__(256) void k_ln_relu_bf16(
    const float* __restrict__ X, int W, const float* __restrict__ g,
    const float* __restrict__ be, short* __restrict__ out, int ldo) {
  ln_relu_body<0>(X, W, g, be, out, ldo);
}
__global__ __launch_bounds__(256) void k_ln_relu_f32(
    const float* __restrict__ X, int W, const float* __restrict__ g,
    const float* __restrict__ be, float* __restrict__ out, int ldo) {
  ln_relu_body<1>(X, W, g, be, out, ldo);
}

extern "C" void kernel_launch(void* const* d_in, const int* in_sizes, int n_in,
                              void* d_out, int out_size, void* d_ws, size_t ws_size,
                              hipStream_t stream) {
  const float* nf      = (const float*)d_in[0];
  const float* Mob     = (const float*)d_in[1];
  const float* W_in1   = (const float*)d_in[2];
  const float* b_in1   = (const float*)d_in[3];
  const float* W_out1  = (const float*)d_in[4];
  const float* b_out1  = (const float*)d_in[5];
  const float* W_self1 = (const float*)d_in[6];
  const float* b_self1 = (const float*)d_in[7];
  const float* g1      = (const float*)d_in[8];
  const float* be1     = (const float*)d_in[9];
  const float* W_in2   = (const float*)d_in[10];
  const float* b_in2   = (const float*)d_in[11];
  const float* W_out2  = (const float*)d_in[12];
  const float* b_out2  = (const float*)d_in[13];
  const float* W_self2 = (const float*)d_in[14];
  const float* b_self2 = (const float*)d_in[15];
  const float* g2      = (const float*)d_in[16];
  const float* be2     = (const float*)d_in[17];

  char* ws = (char*)d_ws;   // ws_size >= 1 GiB (fill evidence); no overlapping buffers
  float* colsum = (float*)(ws);                       // 32 KB
  u32*   colmax = (u32*)(ws + 32768);                 // 32 KB
  short* Mt     = (short*)(ws + 65536);               // [8192][8192] bf16 -> ends 134,283,264
  short* nft    = (short*)(ws + 134283264);           // [256][8192] bf16 (nf^T)
  short* A1cat  = (short*)(ws + 138477568);           // [8192][512]: [A1(256)|nf(256)]
  float* C2f    = (float*)(ws + 146866176);           // [8192][512] f32 (L2 reuses [8192][256])
  short* Acat2  = (short*)(ws + 163643392);           // [8192][768]: [agg2(256)|h1(512)]
  short* T2t    = (short*)(ws + 176226304);           // [256][8192]
  short* Bcat1  = (short*)(ws + 180420608);           // [512][512]: [Wc1^T | Wself1^T]
  short* Bcat2  = (short*)(ws + 180944896);           // [256][768]: [Wout2^T | Wself2^T]
  short* Win2t  = (short*)(ws + 181338112);           // [256][512]
  short* Wout1t = (short*)(ws + 181600256);           // [512][512]
  short* Win1b  = (short*)(ws + 182124544);           // [256][512] bf16 (straight cast)
  float* bias1c = (float*)(ws + 182386688);           // [512]
  float* bias2c = (float*)(ws + 182390784);           // [256]
  short* P1     = (short*)(ws + 188743680);           // 8 x [8192][256] bf16 = 33.5 MB
  short* P2     = (short*)(ws + 222298112);           // 8 x [8192][256] bf16 = 33.5 MB

  hipMemsetAsync(ws, 0, 65536, stream);  // zero colsum + colmax every call

  k_prep_mt<<<dim3(32, 128), 256, 0, stream>>>(Mob, Mt, colsum, colmax);
  k_trans_cast<<<dim3(128, 4), 256, 0, stream>>>(nf, 8192, 256, nft);
  k_cast_nf<<<2048, 256, 0, stream>>>(nf, A1cat);
  k_cast4<<<128, 256, 0, stream>>>(W_in1, Win1b);                       // 256x512
  k_tcast<<<1024, 256, 0, stream>>>(W_out1, 512, 512, Wout1t, 512);
  k_tcast<<<512, 256, 0, stream>>>(W_self1, 256, 512, Bcat1 + 256, 512);
  k_tcast<<<512, 256, 0, stream>>>(W_in2, 512, 256, Win2t, 512);
  k_tcast<<<256, 256, 0, stream>>>(W_out2, 256, 256, Bcat2, 768);
  k_tcast<<<512, 256, 0, stream>>>(W_self2, 512, 256, Bcat2 + 256, 768);
  // Wc1^T = W_out1^T @ W_in1 (A@B^T form): [512][256] into Bcat1 cols 0:256
  k_gemm_raw_n<<<dim3(4, 8), 256, 0, stream>>>(Wout1t, Win1b, 512, 512, 512,
                                               Bcat1, 512);
  k_bias1<<<2, 256, 0, stream>>>(b_in1, W_out1, b_out1, b_self1, bias1c);
  k_addb<<<1, 256, 0, stream>>>(b_out2, b_self2, bias2c);

  // ---- layer 1 (reassociated): G1 = Mt @ nf^T^T  (M=8192,N=256,K=8192, z=8)
  k_gemm_sk128<<<dim3(2, 64, 8), 256, 0, stream>>>(Mt, nft, 1024, NN, NN,
                                                   P1, 256, (size_t)8192 * 256);
  k_sk_reduce_sub<<<2048, 256, 0, stream>>>(P1, 256, (size_t)8192 * 256, 8,
                                            colsum, colmax, A1cat + 256, 512,
                                            A1cat, 512);
  // out1 = [A1|nf] @ [Wc1 ; W_self1] + bias1c   (M=8192,N=512,K=512)
  k_gemm_out_w<<<dim3(4, 128), 256, 0, stream>>>(A1cat, Bcat1, 512, 512, 512,
                                                 C2f, 512, bias1c);
  k_ln_relu_bf16<<<8192, 256, 0, stream>>>(C2f, 512, g1, be1, Acat2 + 256, 768);

  // ---- layer 2 (original order): T2t = W_in2^T@h1^T + b_in2
  k_gemm_bias_n<<<dim3(128, 4), 256, 0, stream>>>(Win2t, Acat2 + 256, 512, 512, 768,
                                                  T2t, NN, b_in2);
  k_gemm_sk128<<<dim3(2, 64, 8), 256, 0, stream>>>(Mt, T2t, 1024, NN, NN,
                                                   P2, 256, (size_t)8192 * 256);
  k_sk_reduce<<<2048, 256, 0, stream>>>(P2, 256, (size_t)8192 * 256, 8,
                                        colsum, colmax, T2t, Acat2, 768);
  k_gemm_out_n<<<dim3(4, 128), 256, 0, stream>>>(Acat2, Bcat2, 768, 768, 768,
                                                 C2f, 256, bias2c);
  k_ln_relu_f32<<<8192, 256, 0, stream>>>(C2f, 256, g2, be2, (float*)d_out, 256);
}

// Round 12
// 324.977 us; speedup vs baseline: 2.9904x; 1.0500x over previous
//
#include <hip/hip_runtime.h>
#include <stdint.h>

typedef short bf16x8 __attribute__((ext_vector_type(8)));
typedef short s16x4 __attribute__((ext_vector_type(4)));
typedef float f32x4 __attribute__((ext_vector_type(4)));
typedef unsigned int u32;

#define EPS_A 1e-8f
#define THR_A 1e-6f
#define NN 8192

static __device__ __forceinline__ short f2bf(float f) {
  u32 u = __float_as_uint(f);
  u = u + 0x7FFFu + ((u >> 16) & 1u);   // RNE, no NaN inputs here
  return (short)(u >> 16);
}
static __device__ __forceinline__ float bf2f(short s) {
  return __uint_as_float(((u32)(unsigned short)s) << 16);
}
// conflict-free LDS offset (shorts): row stride 32 shorts (64B); XOR the 16B-slot
// index (bits 3..5) with the 128B-line index
static __device__ __forceinline__ int swz(int row, int slot8) {
  int off = row * 32 + slot8 * 8;
  return off ^ (((row >> 1) & 7) << 3);
}
// async global->LDS, 16B per lane; DIRECT addrspacecasts (no uintptr_t round-trip!)
static __device__ __forceinline__ void gld16(const short* g, short* l) {
  __builtin_amdgcn_global_load_lds(
      (const __attribute__((address_space(1))) u32*)g,
      (__attribute__((address_space(3))) u32*)l, 16, 0, 0);
}

// ---- single pass over M: transpose-cast -> Mt bf16 [i][j], colsum, colmax
__global__ __launch_bounds__(256) void k_prep_mt(
    const float* __restrict__ M, short* __restrict__ Mt,
    float* __restrict__ colsum, u32* __restrict__ colmax)
{
  __shared__ __align__(16) short tile[256 * 66];
  const int t = threadIdx.x;
  const int i0 = blockIdx.x * 256;
  const int j0 = blockIdx.y * 64;
  const int i = i0 + t;
  float s = 0.f, mx = 0.f;
  #pragma unroll 4
  for (int jj = 0; jj < 64; ++jj) {
    float v = M[(size_t)(j0 + jj) * NN + i];    // coalesced: t -> i
    s += v;
    mx = fmaxf(mx, v);
    tile[t * 66 + jj] = f2bf(v);
  }
  atomicAdd(&colsum[i], s);
  atomicMax(&colmax[i], __float_as_uint(mx));
  __syncthreads();
  #pragma unroll
  for (int p = 0; p < 8; ++p) {
    const int r = p * 32 + (t >> 3);
    const int c = t & 7;
    const u32* src = (const u32*)((const char*)tile + r * 132 + c * 16);
    int4 w = make_int4(src[0], src[1], src[2], src[3]);
    *(int4*)((char*)Mt + (((size_t)(i0 + r) * NN + j0) * 2 + c * 16)) = w;
  }
}

// ---- fused small prep: all weight/feature casts + bias folds in ONE launch
__global__ __launch_bounds__(256) void k_prep_fused(
    const float* __restrict__ nf,
    const float* __restrict__ W_in1, const float* __restrict__ W_out1,
    const float* __restrict__ W_self1, const float* __restrict__ W_in2,
    const float* __restrict__ W_out2, const float* __restrict__ W_self2,
    const float* __restrict__ b_in1, const float* __restrict__ b_out1,
    const float* __restrict__ b_self1, const float* __restrict__ b_out2,
    const float* __restrict__ b_self2,
    short* __restrict__ nft, short* __restrict__ A1cat, short* __restrict__ Win1b,
    short* __restrict__ Wout1t, short* __restrict__ Bcat1, short* __restrict__ Win2t,
    short* __restrict__ Bcat2, float* __restrict__ bias1c, float* __restrict__ bias2c)
{
  int b = blockIdx.x;
  const int t = threadIdx.x;
  if (b < 512) {                       // nf^T: LDS-tiled transpose-cast 8192x256
    __shared__ short tile[64][65];
    const int r0 = (b & 127) * 64, c0 = (b >> 7) * 64;
    #pragma unroll
    for (int p = 0; p < 16; ++p) {
      const int rr = p * 4 + (t >> 6), cc = t & 63;
      tile[rr][cc] = f2bf(nf[(size_t)(r0 + rr) * 256 + c0 + cc]);
    }
    __syncthreads();
    #pragma unroll
    for (int q = 0; q < 16; ++q) {
      const int cc = q * 4 + (t >> 6), rr = t & 63;
      nft[(size_t)(c0 + cc) * 8192 + r0 + rr] = tile[rr][cc];
    }
    return;
  }
  b -= 512;
  if (b < 2048) {                      // nf -> A1cat cols 256:512
    const int idx = b * 256 + t;
    const float4 v = ((const float4*)nf)[idx];
    const int i = idx >> 6;
    const int c = (idx & 63) * 4;
    s16x4 o;
    o.x = f2bf(v.x); o.y = f2bf(v.y); o.z = f2bf(v.z); o.w = f2bf(v.w);
    *(s16x4*)&A1cat[(size_t)i * 512 + 256 + c] = o;
    return;
  }
  b -= 2048;
  if (b < 128) {                       // W_in1 straight cast 256x512
    const int idx = b * 256 + t;
    const float4 v = ((const float4*)W_in1)[idx];
    s16x4 o;
    o.x = f2bf(v.x); o.y = f2bf(v.y); o.z = f2bf(v.z); o.w = f2bf(v.w);
    *(s16x4*)&Win1b[idx * 4] = o;
    return;
  }
  b -= 128;
  if (b < 1024) {                      // W_out1^T 512x512 -> Wout1t ld 512
    const int idx = b * 256 + t;
    const int r = idx >> 9, c = idx & 511;
    Wout1t[(size_t)c * 512 + r] = f2bf(W_out1[idx]);
    return;
  }
  b -= 1024;
  if (b < 512) {                       // W_self1^T 256x512 -> Bcat1+256 ld 512
    const int idx = b * 256 + t;
    const int r = idx >> 9, c = idx & 511;
    Bcat1[(size_t)c * 512 + 256 + r] = f2bf(W_self1[idx]);
    return;
  }
  b -= 512;
  if (b < 512) {                       // W_in2^T 512x256 -> Win2t ld 512
    const int idx = b * 256 + t;
    const int r = idx >> 8, c = idx & 255;
    Win2t[(size_t)c * 512 + r] = f2bf(W_in2[idx]);
    return;
  }
  b -= 512;
  if (b < 256) {                       // W_out2^T 256x256 -> Bcat2 ld 768
    const int idx = b * 256 + t;
    const int r = idx >> 8, c = idx & 255;
    Bcat2[(size_t)c * 768 + r] = f2bf(W_out2[idx]);
    return;
  }
  b -= 256;
  if (b < 512) {                       // W_self2^T 512x256 -> Bcat2+256 ld 768
    const int idx = b * 256 + t;
    const int r = idx >> 8, c = idx & 255;
    Bcat2[(size_t)c * 768 + 256 + r] = f2bf(W_self2[idx]);
    return;
  }
  b -= 512;
  if (b < 2) {                         // bias1c = b_in1@W_out1 + b_out1 + b_self1
    const int n = b * 256 + t;
    float a = b_out1[n] + b_self1[n];
    for (int p = 0; p < 512; ++p) a += b_in1[p] * W_out1[(size_t)p * 512 + n];
    bias1c[n] = a;
    return;
  }
  bias2c[t] = b_out2[t] + b_self2[t];  // last block
}

// ---- 64 x BN GEMM (proven body): EPI 0 += bias0[m] bf16; EPI 2 += bias0[n] fp32;
//      EPI 3 raw bf16
template <int BN, int EPI>
__device__ __forceinline__ void gemm_body(
    const short* __restrict__ A, const short* __restrict__ B, int K, int ldA, int ldB,
    void* __restrict__ Cout, int ldC, const float* __restrict__ bias0)
{
  constexpr int BM = 64;
  constexpr int MI = BM / 32;
  constexpr int NI = BN / 32;
  constexpr int LDP = 40;
  __shared__ __align__(16) short As[BM * LDP];
  __shared__ __align__(16) short Bs[BN * LDP];
  const int t = threadIdx.x;

  const int gx = gridDim.x;
  int flat = blockIdx.y * gx + blockIdx.x;
  const int cpx = (gx * gridDim.y) >> 3;
  flat = (flat & 7) * cpx + (flat >> 3);
  const int bx = flat % gx, by = flat / gx;
  const int m0 = by * BM, n0 = bx * BN;

  const int wid = t >> 6, l = t & 63;
  const int wr = wid >> 1, wc = wid & 1;
  const int lr = l & 15, lk = l >> 4;

  f32x4 acc[MI][NI] = {};

  const int sr = t >> 2;
  const int sc = (t & 3) * 8;
  const short* gA0 = A + (size_t)(m0 + sr) * ldA + sc;
  const short* gB0 = B + (size_t)(n0 + sr) * ldB + sc;
  const short* gB1 = gB0 + (size_t)64 * ldB;

  for (int k0 = 0; k0 < K; k0 += 32) {
    const int4 a0 = *(const int4*)(gA0 + k0);
    const int4 b0 = *(const int4*)(gB0 + k0);
    int4 b1 = make_int4(0, 0, 0, 0);
    if (NI == 4) b1 = *(const int4*)(gB1 + k0);
    __syncthreads();
    *(int4*)&As[sr * LDP + sc] = a0;
    *(int4*)&Bs[sr * LDP + sc] = b0;
    if (NI == 4) *(int4*)&Bs[(64 + sr) * LDP + sc] = b1;
    __syncthreads();

    bf16x8 av[MI], bv[NI];
    #pragma unroll
    for (int mi = 0; mi < MI; ++mi)
      av[mi] = *(const bf16x8*)&As[(wr * (BM / 2) + mi * 16 + lr) * LDP + lk * 8];
    #pragma unroll
    for (int ni = 0; ni < NI; ++ni)
      bv[ni] = *(const bf16x8*)&Bs[(wc * (BN / 2) + ni * 16 + lr) * LDP + lk * 8];
    #pragma unroll
    for (int mi = 0; mi < MI; ++mi)
      #pragma unroll
      for (int ni = 0; ni < NI; ++ni)
        acc[mi][ni] = __builtin_amdgcn_mfma_f32_16x16x32_bf16(av[mi], bv[ni], acc[mi][ni], 0, 0, 0);
  }

  #pragma unroll
  for (int mi = 0; mi < MI; ++mi) {
    #pragma unroll
    for (int r = 0; r < 4; ++r) {
      const int m = m0 + wr * (BM / 2) + mi * 16 + lk * 4 + r;
      float b0 = 0.f;
      if (EPI == 0) b0 = bias0[m];
      #pragma unroll
      for (int ni = 0; ni < NI; ++ni) {
        const int n = n0 + wc * (BN / 2) + ni * 16 + lr;
        float v = acc[mi][ni][r];
        if (EPI == 0) {
          v += b0;
          ((short*)Cout)[(size_t)m * ldC + n] = f2bf(v);
        } else if (EPI == 3) {
          ((short*)Cout)[(size_t)m * ldC + n] = f2bf(v);
        } else {
          v += bias0[n];
          ((float*)Cout)[(size_t)m * ldC + n] = v;
        }
      }
    }
  }
}

__global__ __launch_bounds__(256) void k_gemm_bias_n(
    const short* __restrict__ A, const short* __restrict__ B, int K, int ldA, int ldB,
    void* __restrict__ C, int ldC, const float* __restrict__ bias0) {
  gemm_body<64, 0>(A, B, K, ldA, ldB, C, ldC, bias0);
}
__global__ __launch_bounds__(256) void k_gemm_raw_n(
    const short* __restrict__ A, const short* __restrict__ B, int K, int ldA, int ldB,
    void* __restrict__ C, int ldC) {
  gemm_body<64, 3>(A, B, K, ldA, ldB, C, ldC, nullptr);
}
__global__ __launch_bounds__(256) void k_gemm_out_w(
    const short* __restrict__ A, const short* __restrict__ B, int K, int ldA, int ldB,
    void* __restrict__ C, int ldC, const float* __restrict__ bias0) {
  gemm_body<128, 2>(A, B, K, ldA, ldB, C, ldC, bias0);
}
__global__ __launch_bounds__(256) void k_gemm_out_n(
    const short* __restrict__ A, const short* __restrict__ B, int K, int ldA, int ldB,
    void* __restrict__ C, int ldC, const float* __restrict__ bias0) {
  gemm_body<64, 2>(A, B, K, ldA, ldB, C, ldC, bias0);
}

// ---- 128x128 split-K GEMM, BK=32, global_load_lds staging (m97 structure):
// linear LDS dest + inverse-swizzled per-lane global source + swz() reads.
__global__ __launch_bounds__(256) void k_gemm_sk128(
    const short* __restrict__ A, const short* __restrict__ B, int K, int ldA, int ldB,
    short* __restrict__ P, int ldC, size_t pstride)
{
  __shared__ __align__(16) short As[128 * 32];   // 8 KB each
  __shared__ __align__(16) short Bs[128 * 32];
  const int t = threadIdx.x;

  const int sk = blockIdx.z;
  A += (size_t)sk * K;
  B += (size_t)sk * K;

  const int gx = gridDim.x;
  int flat = blockIdx.y * gx + blockIdx.x;
  const int cpx = (gx * gridDim.y) >> 3;
  flat = (flat & 7) * cpx + (flat >> 3);
  const int bx = flat % gx, by = flat / gx;
  const int m0 = by * 128, n0 = bx * 128;

  const int wid = t >> 6, l = t & 63;
  const int wr = wid >> 1, wc = wid & 1;
  const int lr = l & 15, lk = l >> 4;

  f32x4 acc[4][4] = {};

  // staging geometry: waves 0,1 -> As; waves 2,3 -> Bs. Each wave: 4 KB = 4 chunks
  // of 1 KB (64 lanes x 16B). Linear unit u = (wid&1)*256 + c*64 + l holds the
  // content swz^-1(u): off=u*8; msk=((off>>6)&7)<<3; orig=off^msk; row=orig>>5,
  // slot=(orig>>3)&3  (exact inverse since swz's XOR never touches bits >=6).
  const int side = wid >> 1;
  const int hu = (wid & 1) * 256;
  const short* Xp = side ? B : A;
  const int ldX = side ? ldB : ldA;
  const int x0 = side ? n0 : m0;
  short* dbase = (side ? Bs : As) + hu * 8;
  const short *g0, *g1, *g2, *g3;
  {
    int u, off, msk, orig, row, slot;
    u = hu + 0 * 64 + l; off = u * 8; msk = ((off >> 6) & 7) << 3; orig = off ^ msk;
    row = orig >> 5; slot = (orig >> 3) & 3;
    g0 = Xp + (size_t)(x0 + row) * ldX + slot * 8;
    u = hu + 1 * 64 + l; off = u * 8; msk = ((off >> 6) & 7) << 3; orig = off ^ msk;
    row = orig >> 5; slot = (orig >> 3) & 3;
    g1 = Xp + (size_t)(x0 + row) * ldX + slot * 8;
    u = hu + 2 * 64 + l; off = u * 8; msk = ((off >> 6) & 7) << 3; orig = off ^ msk;
    row = orig >> 5; slot = (orig >> 3) & 3;
    g2 = Xp + (size_t)(x0 + row) * ldX + slot * 8;
    u = hu + 3 * 64 + l; off = u * 8; msk = ((off >> 6) & 7) << 3; orig = off ^ msk;
    row = orig >> 5; slot = (orig >> 3) & 3;
    g3 = Xp + (size_t)(x0 + row) * ldX + slot * 8;
  }

  for (int k0 = 0; k0 < K; k0 += 32) {
    __syncthreads();                    // previous iteration's reads done
    gld16(g0 + k0, dbase);
    gld16(g1 + k0, dbase + 512);
    gld16(g2 + k0, dbase + 1024);
    gld16(g3 + k0, dbase + 1536);
    __syncthreads();                    // vmcnt(0) drained by compiler before barrier

    bf16x8 av[4], bv[4];
    #pragma unroll
    for (int mi = 0; mi < 4; ++mi)
      av[mi] = *(const bf16x8*)&As[swz(wr * 64 + mi * 16 + lr, lk)];
    #pragma unroll
    for (int ni = 0; ni < 4; ++ni)
      bv[ni] = *(const bf16x8*)&Bs[swz(wc * 64 + ni * 16 + lr, lk)];
    #pragma unroll
    for (int mi = 0; mi < 4; ++mi)
      #pragma unroll
      for (int ni = 0; ni < 4; ++ni)
        acc[mi][ni] = __builtin_amdgcn_mfma_f32_16x16x32_bf16(av[mi], bv[ni], acc[mi][ni], 0, 0, 0);
  }

  short* outp = P + pstride * sk;
  #pragma unroll
  for (int mi = 0; mi < 4; ++mi) {
    #pragma unroll
    for (int r = 0; r < 4; ++r) {
      const int m = m0 + wr * 64 + mi * 16 + lk * 4 + r;
      #pragma unroll
      for (int ni = 0; ni < 4; ++ni) {
        const int n = n0 + wc * 64 + ni * 16 + lr;
        outp[(size_t)m * ldC + n] = f2bf(acc[mi][ni][r]);
      }
    }
  }
}

// ---- reduce S partials + normalize; fallback substitutes raw h row (coalesced)
__global__ __launch_bounds__(256) void k_sk_reduce_sub(
    const short* __restrict__ P, int N, size_t pstride, int S,
    const float* __restrict__ colsum, const u32* __restrict__ colmax,
    const short* __restrict__ hraw, int ldh,
    short* __restrict__ out, int ldo)
{
  const int idx = blockIdx.x * 256 + threadIdx.x;
  const int nq = N >> 2;
  const int m = idx / nq;
  const int c4 = (idx - m * nq) * 4;
  const size_t base = (size_t)m * N + c4;
  float a0 = 0.f, a1 = 0.f, a2 = 0.f, a3 = 0.f;
  for (int s = 0; s < S; ++s) {
    s16x4 v = *(const s16x4*)&P[pstride * s + base];
    a0 += bf2f(v.x); a1 += bf2f(v.y); a2 += bf2f(v.z); a3 += bf2f(v.w);
  }
  const float cs = colsum[m];
  const float rc = 1.f / (cs + EPS_A);
  const float rcw = rc / (cs * rc + EPS_A);
  const bool he = __uint_as_float(colmax[m]) * rc > THR_A;
  s16x4 o;
  if (he) {
    o.x = f2bf(a0 * rcw); o.y = f2bf(a1 * rcw);
    o.z = f2bf(a2 * rcw); o.w = f2bf(a3 * rcw);
  } else {
    o = *(const s16x4*)&hraw[(size_t)m * ldh + c4];
  }
  *(s16x4*)&out[(size_t)m * ldo + c4] = o;
}

// ---- reduce S partials + normalize; fallback gathers T^T (rare, ballot-skipped)
__global__ __launch_bounds__(256) void k_sk_reduce(
    const short* __restrict__ P, int N, size_t pstride, int S,
    const float* __restrict__ colsum, const u32* __restrict__ colmax,
    const short* __restrict__ Tfall, short* __restrict__ out, int ldo)
{
  const int idx = blockIdx.x * 256 + threadIdx.x;
  const int nq = N >> 2;
  const int m = idx / nq;
  const int c4 = (idx - m * nq) * 4;
  const size_t base = (size_t)m * N + c4;
  float a0 = 0.f, a1 = 0.f, a2 = 0.f, a3 = 0.f;
  for (int s = 0; s < S; ++s) {
    s16x4 v = *(const s16x4*)&P[pstride * s + base];
    a0 += bf2f(v.x); a1 += bf2f(v.y); a2 += bf2f(v.z); a3 += bf2f(v.w);
  }
  const float cs = colsum[m];
  const float rc = 1.f / (cs + EPS_A);
  const float rcw = rc / (cs * rc + EPS_A);
  const bool he = __uint_as_float(colmax[m]) * rc > THR_A;
  a0 *= rcw; a1 *= rcw; a2 *= rcw; a3 *= rcw;
  if (__ballot(!he)) {
    if (!he) {
      a0 = bf2f(Tfall[(size_t)(c4 + 0) * NN + m]);
      a1 = bf2f(Tfall[(size_t)(c4 + 1) * NN + m]);
      a2 = bf2f(Tfall[(size_t)(c4 + 2) * NN + m]);
      a3 = bf2f(Tfall[(size_t)(c4 + 3) * NN + m]);
    }
  }
  s16x4 o;
  o.x = f2bf(a0); o.y = f2bf(a1); o.z = f2bf(a2); o.w = f2bf(a3);
  *(s16x4*)&out[(size_t)m * ldo + c4] = o;
}

// ---- row LayerNorm + ReLU, fp32 in.  MODE 0: bf16 out (ld-strided), MODE 1: fp32 out
template <int MODE>
__device__ __forceinline__ void ln_relu_body(
    const float* __restrict__ X, int W,
    const float* __restrict__ g, const float* __restrict__ be,
    void* __restrict__ out, int ldo)
{
  const int row = blockIdx.x;
  const int t = threadIdx.x;
  const float* x = X + (size_t)row * W;
  float v0 = x[t], v1 = 0.f;
  float s = v0, ss = v0 * v0;
  if (W == 512) { v1 = x[t + 256]; s += v1; ss += v1 * v1; }
  #pragma unroll
  for (int off = 32; off; off >>= 1) {
    s += __shfl_down(s, off);
    ss += __shfl_down(ss, off);
  }
  __shared__ float red[8];
  const int wid = t >> 6;
  if ((t & 63) == 0) { red[wid] = s; red[4 + wid] = ss; }
  __syncthreads();
  s = red[0] + red[1] + red[2] + red[3];
  ss = red[4] + red[5] + red[6] + red[7];
  const float mu = s / W;
  const float var = ss / W - mu * mu;
  const float sc = rsqrtf(var + 1e-5f);
  float y = fmaxf((v0 - mu) * sc * g[t] + be[t], 0.f);
  if (MODE == 0) ((short*)out)[(size_t)row * ldo + t] = f2bf(y);
  else           ((float*)out)[(size_t)row * ldo + t] = y;
  if (W == 512) {
    float y1 = fmaxf((v1 - mu) * sc * g[t + 256] + be[t + 256], 0.f);
    if (MODE == 0) ((short*)out)[(size_t)row * ldo + t + 256] = f2bf(y1);
    else           ((float*)out)[(size_t)row * ldo + t + 256] = y1;
  }
}

__global__ __launch_bounds__(256) void k_ln_relu_bf16(
    const float* __restrict__ X, int W, const float* __restrict__ g,
    const float* __restrict__ be, short* __restrict__ out, int ldo) {
  ln_relu_body<0>(X, W, g, be, out, ldo);
}
__global__ __launch_bounds__(256) void k_ln_relu_f32(
    const float* __restrict__ X, int W, const float* __restrict__ g,
    const float* __restrict__ be, float* __restrict__ out, int ldo) {
  ln_relu_body<1>(X, W, g, be, out, ldo);
}

extern "C" void kernel_launch(void* const* d_in, const int* in_sizes, int n_in,
                              void* d_out, int out_size, void* d_ws, size_t ws_size,
                              hipStream_t stream) {
  const float* nf      = (const float*)d_in[0];
  const float* Mob     = (const float*)d_in[1];
  const float* W_in1   = (const float*)d_in[2];
  const float* b_in1   = (const float*)d_in[3];
  const float* W_out1  = (const float*)d_in[4];
  const float* b_out1  = (const float*)d_in[5];
  const float* W_self1 = (const float*)d_in[6];
  const float* b_self1 = (const float*)d_in[7];
  const float* g1      = (const float*)d_in[8];
  const float* be1     = (const float*)d_in[9];
  const float* W_in2   = (const float*)d_in[10];
  const float* b_in2   = (const float*)d_in[11];
  const float* W_out2  = (const float*)d_in[12];
  const float* b_out2  = (const float*)d_in[13];
  const float* W_self2 = (const float*)d_in[14];
  const float* b_self2 = (const float*)d_in[15];
  const float* g2      = (const float*)d_in[16];
  const float* be2     = (const float*)d_in[17];

  char* ws = (char*)d_ws;
  float* colsum = (float*)(ws);
  u32*   colmax = (u32*)(ws + 32768);
  short* Mt     = (short*)(ws + 65536);               // [8192][8192] bf16
  short* nft    = (short*)(ws + 134283264);           // [256][8192]
  short* A1cat  = (short*)(ws + 138477568);           // [8192][512]: [A1|nf]
  float* C2f    = (float*)(ws + 146866176);           // [8192][512] f32
  short* Acat2  = (short*)(ws + 163643392);           // [8192][768]: [agg2|h1]
  short* T2t    = (short*)(ws + 176226304);           // [256][8192]
  short* Bcat1  = (short*)(ws + 180420608);           // [512][512]: [Wc1^T|Wself1^T]
  short* Bcat2  = (short*)(ws + 180944896);           // [256][768]
  short* Win2t  = (short*)(ws + 181338112);           // [256][512]
  short* Wout1t = (short*)(ws + 181600256);           // [512][512]
  short* Win1b  = (short*)(ws + 182124544);           // [256][512]
  float* bias1c = (float*)(ws + 182386688);           // [512]
  float* bias2c = (float*)(ws + 182390784);           // [256]
  short* P1     = (short*)(ws + 188743680);           // 8 x [8192][256] bf16
  short* P2     = (short*)(ws + 222298112);           // 8 x [8192][256] bf16

  hipMemsetAsync(ws, 0, 65536, stream);  // zero colsum + colmax every call

  k_prep_mt<<<dim3(32, 128), 256, 0, stream>>>(Mob, Mt, colsum, colmax);
  k_prep_fused<<<5507, 256, 0, stream>>>(nf, W_in1, W_out1, W_self1, W_in2, W_out2,
                                         W_self2, b_in1, b_out1, b_self1, b_out2,
                                         b_self2, nft, A1cat, Win1b, Wout1t, Bcat1,
                                         Win2t, Bcat2, bias1c, bias2c);
  // Wc1^T = W_out1^T @ W_in1 : [512][256] into Bcat1 cols 0:256
  k_gemm_raw_n<<<dim3(4, 8), 256, 0, stream>>>(Wout1t, Win1b, 512, 512, 512,
                                               Bcat1, 512);

  // ---- layer 1 (reassociated): G1 = Mt @ nft^T  (M=8192,N=256,K=8192, z=8)
  k_gemm_sk128<<<dim3(2, 64, 8), 256, 0, stream>>>(Mt, nft, 1024, NN, NN,
                                                   P1, 256, (size_t)8192 * 256);
  k_sk_reduce_sub<<<2048, 256, 0, stream>>>(P1, 256, (size_t)8192 * 256, 8,
                                            colsum, colmax, A1cat + 256, 512,
                                            A1cat, 512);
  k_gemm_out_w<<<dim3(4, 128), 256, 0, stream>>>(A1cat, Bcat1, 512, 512, 512,
                                                 C2f, 512, bias1c);
  k_ln_relu_bf16<<<8192, 256, 0, stream>>>(C2f, 512, g1, be1, Acat2 + 256, 768);

  // ---- layer 2: T2t = W_in2^T@h1^T + b_in2; agg2; out2; LN
  k_gemm_bias_n<<<dim3(128, 4), 256, 0, stream>>>(Win2t, Acat2 + 256, 512, 512, 768,
                                                  T2t, NN, b_in2);
  k_gemm_sk128<<<dim3(2, 64, 8), 256, 0, stream>>>(Mt, T2t, 1024, NN, NN,
                                                   P2, 256, (size_t)8192 * 256);
  k_sk_reduce<<<2048, 256, 0, stream>>>(P2, 256, (size_t)8192 * 256, 8,
                                        colsum, colmax, T2t, Acat2, 768);
  k_gemm_out_n<<<dim3(4, 128), 256, 0, stream>>>(Acat2, Bcat2, 768, 768, 768,
                                                 C2f, 256, bias2c);
  k_ln_relu_f32<<<8192, 256, 0, stream>>>(C2f, 256, g2, be2, (float*)d_out, 256);
}

// Round 13
// 312.310 us; speedup vs baseline: 3.1117x; 1.0406x over previous
//
#include <hip/hip_runtime.h>
#include <stdint.h>

typedef short bf16x8 __attribute__((ext_vector_type(8)));
typedef short s16x4 __attribute__((ext_vector_type(4)));
typedef float f32x4 __attribute__((ext_vector_type(4)));
typedef unsigned int u32;

#define EPS_A 1e-8f
#define THR_A 1e-6f
#define NN 8192

static __device__ __forceinline__ short f2bf(float f) {
  u32 u = __float_as_uint(f);
  u = u + 0x7FFFu + ((u >> 16) & 1u);   // RNE, no NaN inputs here
  return (short)(u >> 16);
}
static __device__ __forceinline__ float bf2f(short s) {
  return __uint_as_float(((u32)(unsigned short)s) << 16);
}
// async global->LDS, 16B per lane; DIRECT addrspacecasts (proven round 12)
static __device__ __forceinline__ void gld16(const short* g, short* l) {
  __builtin_amdgcn_global_load_lds(
      (const __attribute__((address_space(1))) u32*)g,
      (__attribute__((address_space(3))) u32*)l, 16, 0, 0);
}

// ---- fused prep: Mt transpose-cast + colsum/colmax, all weight/feature casts,
//      bias folds — ONE launch, 9603 blocks
__global__ __launch_bounds__(256) void k_prep_all(
    const float* __restrict__ Mob, const float* __restrict__ nf,
    const float* __restrict__ W_in1, const float* __restrict__ W_out1,
    const float* __restrict__ W_self1, const float* __restrict__ W_in2,
    const float* __restrict__ W_out2, const float* __restrict__ W_self2,
    const float* __restrict__ b_in1, const float* __restrict__ b_out1,
    const float* __restrict__ b_self1, const float* __restrict__ b_out2,
    const float* __restrict__ b_self2,
    short* __restrict__ Mt, float* __restrict__ colsum, u32* __restrict__ colmax,
    short* __restrict__ nft, short* __restrict__ A1cat, short* __restrict__ Win1b,
    short* __restrict__ Wout1t, short* __restrict__ Bcat1, short* __restrict__ Win2t,
    short* __restrict__ Bcat2, float* __restrict__ bias1c, float* __restrict__ bias2c)
{
  __shared__ __align__(16) short sbuf[256 * 66];
  int b = blockIdx.x;
  const int t = threadIdx.x;
  if (b < 4096) {                      // Mt: transpose-cast + colsum/colmax
    const int i0 = (b & 31) * 256;
    const int j0 = (b >> 5) * 64;
    const int i = i0 + t;
    float s = 0.f, mx = 0.f;
    #pragma unroll 4
    for (int jj = 0; jj < 64; ++jj) {
      float v = Mob[(size_t)(j0 + jj) * NN + i];   // coalesced: t -> i
      s += v;
      mx = fmaxf(mx, v);
      sbuf[t * 66 + jj] = f2bf(v);
    }
    atomicAdd(&colsum[i], s);
    atomicMax(&colmax[i], __float_as_uint(mx));
    __syncthreads();
    #pragma unroll
    for (int p = 0; p < 8; ++p) {
      const int r = p * 32 + (t >> 3);
      const int c = t & 7;
      const u32* src = (const u32*)((const char*)sbuf + r * 132 + c * 16);
      int4 w = make_int4(src[0], src[1], src[2], src[3]);
      *(int4*)((char*)Mt + (((size_t)(i0 + r) * NN + j0) * 2 + c * 16)) = w;
    }
    return;
  }
  b -= 4096;
  if (b < 512) {                       // nf^T: LDS-tiled transpose-cast 8192x256
    short (*tile)[65] = (short(*)[65])sbuf;
    const int r0 = (b & 127) * 64, c0 = (b >> 7) * 64;
    #pragma unroll
    for (int p = 0; p < 16; ++p) {
      const int rr = p * 4 + (t >> 6), cc = t & 63;
      tile[rr][cc] = f2bf(nf[(size_t)(r0 + rr) * 256 + c0 + cc]);
    }
    __syncthreads();
    #pragma unroll
    for (int q = 0; q < 16; ++q) {
      const int cc = q * 4 + (t >> 6), rr = t & 63;
      nft[(size_t)(c0 + cc) * 8192 + r0 + rr] = tile[rr][cc];
    }
    return;
  }
  b -= 512;
  if (b < 2048) {                      // nf -> A1cat cols 256:512
    const int idx = b * 256 + t;
    const float4 v = ((const float4*)nf)[idx];
    const int i = idx >> 6;
    const int c = (idx & 63) * 4;
    s16x4 o;
    o.x = f2bf(v.x); o.y = f2bf(v.y); o.z = f2bf(v.z); o.w = f2bf(v.w);
    *(s16x4*)&A1cat[(size_t)i * 512 + 256 + c] = o;
    return;
  }
  b -= 2048;
  if (b < 128) {                       // W_in1 straight cast 256x512
    const int idx = b * 256 + t;
    const float4 v = ((const float4*)W_in1)[idx];
    s16x4 o;
    o.x = f2bf(v.x); o.y = f2bf(v.y); o.z = f2bf(v.z); o.w = f2bf(v.w);
    *(s16x4*)&Win1b[idx * 4] = o;
    return;
  }
  b -= 128;
  if (b < 1024) {                      // W_out1^T 512x512 -> Wout1t ld 512
    const int idx = b * 256 + t;
    const int r = idx >> 9, c = idx & 511;
    Wout1t[(size_t)c * 512 + r] = f2bf(W_out1[idx]);
    return;
  }
  b -= 1024;
  if (b < 512) {                       // W_self1^T 256x512 -> Bcat1+256 ld 512
    const int idx = b * 256 + t;
    const int r = idx >> 9, c = idx & 511;
    Bcat1[(size_t)c * 512 + 256 + r] = f2bf(W_self1[idx]);
    return;
  }
  b -= 512;
  if (b < 512) {                       // W_in2^T 512x256 -> Win2t ld 512
    const int idx = b * 256 + t;
    const int r = idx >> 8, c = idx & 255;
    Win2t[(size_t)c * 512 + r] = f2bf(W_in2[idx]);
    return;
  }
  b -= 512;
  if (b < 256) {                       // W_out2^T 256x256 -> Bcat2 ld 768
    const int idx = b * 256 + t;
    const int r = idx >> 8, c = idx & 255;
    Bcat2[(size_t)c * 768 + r] = f2bf(W_out2[idx]);
    return;
  }
  b -= 256;
  if (b < 512) {                       // W_self2^T 512x256 -> Bcat2+256 ld 768
    const int idx = b * 256 + t;
    const int r = idx >> 8, c = idx & 255;
    Bcat2[(size_t)c * 768 + 256 + r] = f2bf(W_self2[idx]);
    return;
  }
  b -= 512;
  if (b < 2) {                         // bias1c = b_in1@W_out1 + b_out1 + b_self1
    const int n = b * 256 + t;
    float a = b_out1[n] + b_self1[n];
    for (int p = 0; p < 512; ++p) a += b_in1[p] * W_out1[(size_t)p * 512 + n];
    bias1c[n] = a;
    return;
  }
  bias2c[t] = b_out2[t] + b_self2[t];  // last block
}

// ---- 64 x BN GEMM (proven body): EPI 0 += bias0[m] bf16; EPI 2 += bias0[n] fp32;
//      EPI 3 raw bf16
template <int BN, int EPI>
__device__ __forceinline__ void gemm_body(
    const short* __restrict__ A, const short* __restrict__ B, int K, int ldA, int ldB,
    void* __restrict__ Cout, int ldC, const float* __restrict__ bias0)
{
  constexpr int BM = 64;
  constexpr int MI = BM / 32;
  constexpr int NI = BN / 32;
  constexpr int LDP = 40;
  __shared__ __align__(16) short As[BM * LDP];
  __shared__ __align__(16) short Bs[BN * LDP];
  const int t = threadIdx.x;

  const int gx = gridDim.x;
  int flat = blockIdx.y * gx + blockIdx.x;
  const int cpx = (gx * gridDim.y) >> 3;
  flat = (flat & 7) * cpx + (flat >> 3);
  const int bx = flat % gx, by = flat / gx;
  const int m0 = by * BM, n0 = bx * BN;

  const int wid = t >> 6, l = t & 63;
  const int wr = wid >> 1, wc = wid & 1;
  const int lr = l & 15, lk = l >> 4;

  f32x4 acc[MI][NI] = {};

  const int sr = t >> 2;
  const int sc = (t & 3) * 8;
  const short* gA0 = A + (size_t)(m0 + sr) * ldA + sc;
  const short* gB0 = B + (size_t)(n0 + sr) * ldB + sc;
  const short* gB1 = gB0 + (size_t)64 * ldB;

  for (int k0 = 0; k0 < K; k0 += 32) {
    const int4 a0 = *(const int4*)(gA0 + k0);
    const int4 b0 = *(const int4*)(gB0 + k0);
    int4 b1 = make_int4(0, 0, 0, 0);
    if (NI == 4) b1 = *(const int4*)(gB1 + k0);
    __syncthreads();
    *(int4*)&As[sr * LDP + sc] = a0;
    *(int4*)&Bs[sr * LDP + sc] = b0;
    if (NI == 4) *(int4*)&Bs[(64 + sr) * LDP + sc] = b1;
    __syncthreads();

    bf16x8 av[MI], bv[NI];
    #pragma unroll
    for (int mi = 0; mi < MI; ++mi)
      av[mi] = *(const bf16x8*)&As[(wr * (BM / 2) + mi * 16 + lr) * LDP + lk * 8];
    #pragma unroll
    for (int ni = 0; ni < NI; ++ni)
      bv[ni] = *(const bf16x8*)&Bs[(wc * (BN / 2) + ni * 16 + lr) * LDP + lk * 8];
    #pragma unroll
    for (int mi = 0; mi < MI; ++mi)
      #pragma unroll
      for (int ni = 0; ni < NI; ++ni)
        acc[mi][ni] = __builtin_amdgcn_mfma_f32_16x16x32_bf16(av[mi], bv[ni], acc[mi][ni], 0, 0, 0);
  }

  #pragma unroll
  for (int mi = 0; mi < MI; ++mi) {
    #pragma unroll
    for (int r = 0; r < 4; ++r) {
      const int m = m0 + wr * (BM / 2) + mi * 16 + lk * 4 + r;
      float b0 = 0.f;
      if (EPI == 0) b0 = bias0[m];
      #pragma unroll
      for (int ni = 0; ni < NI; ++ni) {
        const int n = n0 + wc * (BN / 2) + ni * 16 + lr;
        float v = acc[mi][ni][r];
        if (EPI == 0) {
          v += b0;
          ((short*)Cout)[(size_t)m * ldC + n] = f2bf(v);
        } else if (EPI == 3) {
          ((short*)Cout)[(size_t)m * ldC + n] = f2bf(v);
        } else {
          v += bias0[n];
          ((float*)Cout)[(size_t)m * ldC + n] = v;
        }
      }
    }
  }
}

__global__ __launch_bounds__(256) void k_gemm_bias_n(
    const short* __restrict__ A, const short* __restrict__ B, int K, int ldA, int ldB,
    void* __restrict__ C, int ldC, const float* __restrict__ bias0) {
  gemm_body<64, 0>(A, B, K, ldA, ldB, C, ldC, bias0);
}
__global__ __launch_bounds__(256) void k_gemm_raw_n(
    const short* __restrict__ A, const short* __restrict__ B, int K, int ldA, int ldB,
    void* __restrict__ C, int ldC) {
  gemm_body<64, 3>(A, B, K, ldA, ldB, C, ldC, nullptr);
}
__global__ __launch_bounds__(256) void k_gemm_out_w(
    const short* __restrict__ A, const short* __restrict__ B, int K, int ldA, int ldB,
    void* __restrict__ C, int ldC, const float* __restrict__ bias0) {
  gemm_body<128, 2>(A, B, K, ldA, ldB, C, ldC, bias0);
}
__global__ __launch_bounds__(256) void k_gemm_out_n(
    const short* __restrict__ A, const short* __restrict__ B, int K, int ldA, int ldB,
    void* __restrict__ C, int ldC, const float* __restrict__ bias0) {
  gemm_body<64, 2>(A, B, K, ldA, ldB, C, ldC, bias0);
}

// ---- 128x128 split-K GEMM, BK=64, gld_lds staging, staggered circular K-loop.
// LDS layout: [128 rows][64 shorts]; logical (row,slot) at unit row*8+(slot^(row&7)).
// Staging: linear unit u -> source (row=u>>3, col-slot=(u&7)^(row&7)); per-wave
// 8 chunks of 1KB; source ptr advances 8 rows per chunk (uniform stride).
__global__ __launch_bounds__(256) void k_gemm_sk128(
    const short* __restrict__ A, const short* __restrict__ B, int K, int ldA, int ldB,
    short* __restrict__ P, int ldC, size_t pstride)
{
  __shared__ __align__(16) short As[128 * 64];   // 16 KB each
  __shared__ __align__(16) short Bs[128 * 64];
  const int t = threadIdx.x;

  const int sk = blockIdx.z;
  A += (size_t)sk * K;
  B += (size_t)sk * K;

  const int gx = gridDim.x;
  int flat = blockIdx.y * gx + blockIdx.x;
  const int cpx = (gx * gridDim.y) >> 3;
  flat = (flat & 7) * cpx + (flat >> 3);
  const int bx = flat % gx, by = flat / gx;
  const int m0 = by * 128, n0 = bx * 128;

  const int wid = t >> 6, l = t & 63;
  const int wr = wid >> 1, wc = wid & 1;
  const int lr = l & 15, lk = l >> 4;

  f32x4 acc[4][4] = {};

  // staging: waves 0,1 -> As rows [0,64),[64,128); waves 2,3 -> Bs same
  const int side = wid >> 1;
  const int hrow = (wid & 1) * 64;             // wave-uniform row base
  const short* Xp = side ? B : A;
  const int ldX = side ? ldB : ldA;
  const int x0 = side ? n0 : m0;
  short* dbase = (side ? Bs : As) + hrow * 64; // wave-uniform LDS base
  const int lrow = l >> 3, lcol = l & 7;
  const short* g0 = Xp + (size_t)(x0 + hrow + lrow) * ldX + (lcol ^ lrow) * 8;
  const size_t st8 = (size_t)8 * ldX;          // +8 rows per chunk

  const int niters = K >> 6;                   // power of 2 (16 for K=1024)
  int kk = (flat + sk * 3) & (niters - 1);     // staggered start de-correlates drains

  for (int it = 0; it < niters; ++it) {
    const int koff = kk << 6;
    kk = (kk + 1) & (niters - 1);
    __syncthreads();                           // previous iteration's reads done
    gld16(g0 + koff,            dbase);
    gld16(g0 + koff + st8,      dbase + 512);
    gld16(g0 + koff + 2 * st8,  dbase + 1024);
    gld16(g0 + koff + 3 * st8,  dbase + 1536);
    gld16(g0 + koff + 4 * st8,  dbase + 2048);
    gld16(g0 + koff + 5 * st8,  dbase + 2560);
    gld16(g0 + koff + 6 * st8,  dbase + 3072);
    gld16(g0 + koff + 7 * st8,  dbase + 3584);
    __syncthreads();                           // compiler drains vmcnt before barrier

    #pragma unroll
    for (int ks = 0; ks < 2; ++ks) {
      bf16x8 av[4], bv[4];
      #pragma unroll
      for (int mi = 0; mi < 4; ++mi) {
        const int row = wr * 64 + mi * 16 + lr;
        av[mi] = *(const bf16x8*)&As[row * 64 + ((ks * 4 + lk) ^ (lr & 7)) * 8];
      }
      #pragma unroll
      for (int ni = 0; ni < 4; ++ni) {
        const int row = wc * 64 + ni * 16 + lr;
        bv[ni] = *(const bf16x8*)&Bs[row * 64 + ((ks * 4 + lk) ^ (lr & 7)) * 8];
      }
      #pragma unroll
      for (int mi = 0; mi < 4; ++mi)
        #pragma unroll
        for (int ni = 0; ni < 4; ++ni)
          acc[mi][ni] = __builtin_amdgcn_mfma_f32_16x16x32_bf16(av[mi], bv[ni], acc[mi][ni], 0, 0, 0);
    }
  }

  short* outp = P + pstride * sk;
  #pragma unroll
  for (int mi = 0; mi < 4; ++mi) {
    #pragma unroll
    for (int r = 0; r < 4; ++r) {
      const int m = m0 + wr * 64 + mi * 16 + lk * 4 + r;
      #pragma unroll
      for (int ni = 0; ni < 4; ++ni) {
        const int n = n0 + wc * 64 + ni * 16 + lr;
        outp[(size_t)m * ldC + n] = f2bf(acc[mi][ni][r]);
      }
    }
  }
}

// ---- reduce S partials + normalize; fallback substitutes raw h row (coalesced)
__global__ __launch_bounds__(256) void k_sk_reduce_sub(
    const short* __restrict__ P, int N, size_t pstride, int S,
    const float* __restrict__ colsum, const u32* __restrict__ colmax,
    const short* __restrict__ hraw, int ldh,
    short* __restrict__ out, int ldo)
{
  const int idx = blockIdx.x * 256 + threadIdx.x;
  const int nq = N >> 2;
  const int m = idx / nq;
  const int c4 = (idx - m * nq) * 4;
  const size_t base = (size_t)m * N + c4;
  float a0 = 0.f, a1 = 0.f, a2 = 0.f, a3 = 0.f;
  for (int s = 0; s < S; ++s) {
    s16x4 v = *(const s16x4*)&P[pstride * s + base];
    a0 += bf2f(v.x); a1 += bf2f(v.y); a2 += bf2f(v.z); a3 += bf2f(v.w);
  }
  const float cs = colsum[m];
  const float rc = 1.f / (cs + EPS_A);
  const float rcw = rc / (cs * rc + EPS_A);
  const bool he = __uint_as_float(colmax[m]) * rc > THR_A;
  s16x4 o;
  if (he) {
    o.x = f2bf(a0 * rcw); o.y = f2bf(a1 * rcw);
    o.z = f2bf(a2 * rcw); o.w = f2bf(a3 * rcw);
  } else {
    o = *(const s16x4*)&hraw[(size_t)m * ldh + c4];
  }
  *(s16x4*)&out[(size_t)m * ldo + c4] = o;
}

// ---- reduce S partials + normalize; fallback gathers T^T (rare, ballot-skipped)
__global__ __launch_bounds__(256) void k_sk_reduce(
    const short* __restrict__ P, int N, size_t pstride, int S,
    const float* __restrict__ colsum, const u32* __restrict__ colmax,
    const short* __restrict__ Tfall, short* __restrict__ out, int ldo)
{
  const int idx = blockIdx.x * 256 + threadIdx.x;
  const int nq = N >> 2;
  const int m = idx / nq;
  const int c4 = (idx - m * nq) * 4;
  const size_t base = (size_t)m * N + c4;
  float a0 = 0.f, a1 = 0.f, a2 = 0.f, a3 = 0.f;
  for (int s = 0; s < S; ++s) {
    s16x4 v = *(const s16x4*)&P[pstride * s + base];
    a0 += bf2f(v.x); a1 += bf2f(v.y); a2 += bf2f(v.z); a3 += bf2f(v.w);
  }
  const float cs = colsum[m];
  const float rc = 1.f / (cs + EPS_A);
  const float rcw = rc / (cs * rc + EPS_A);
  const bool he = __uint_as_float(colmax[m]) * rc > THR_A;
  a0 *= rcw; a1 *= rcw; a2 *= rcw; a3 *= rcw;
  if (__ballot(!he)) {
    if (!he) {
      a0 = bf2f(Tfall[(size_t)(c4 + 0) * NN + m]);
      a1 = bf2f(Tfall[(size_t)(c4 + 1) * NN + m]);
      a2 = bf2f(Tfall[(size_t)(c4 + 2) * NN + m]);
      a3 = bf2f(Tfall[(size_t)(c4 + 3) * NN + m]);
    }
  }
  s16x4 o;
  o.x = f2bf(a0); o.y = f2bf(a1); o.z = f2bf(a2); o.w = f2bf(a3);
  *(s16x4*)&out[(size_t)m * ldo + c4] = o;
}

// ---- row LayerNorm + ReLU, fp32 in.  MODE 0: bf16 out (ld-strided), MODE 1: fp32 out
template <int MODE>
__device__ __forceinline__ void ln_relu_body(
    const float* __restrict__ X, int W,
    const float* __restrict__ g, const float* __restrict__ be,
    void* __restrict__ out, int ldo)
{
  const int row = blockIdx.x;
  const int t = threadIdx.x;
  const float* x = X + (size_t)row * W;
  float v0 = x[t], v1 = 0.f;
  float s = v0, ss = v0 * v0;
  if (W == 512) { v1 = x[t + 256]; s += v1; ss += v1 * v1; }
  #pragma unroll
  for (int off = 32; off; off >>= 1) {
    s += __shfl_down(s, off);
    ss += __shfl_down(ss, off);
  }
  __shared__ float red[8];
  const int wid = t >> 6;
  if ((t & 63) == 0) { red[wid] = s; red[4 + wid] = ss; }
  __syncthreads();
  s = red[0] + red[1] + red[2] + red[3];
  ss = red[4] + red[5] + red[6] + red[7];
  const float mu = s / W;
  const float var = ss / W - mu * mu;
  const float sc = rsqrtf(var + 1e-5f);
  float y = fmaxf((v0 - mu) * sc * g[t] + be[t], 0.f);
  if (MODE == 0) ((short*)out)[(size_t)row * ldo + t] = f2bf(y);
  else           ((float*)out)[(size_t)row * ldo + t] = y;
  if (W == 512) {
    float y1 = fmaxf((v1 - mu) * sc * g[t + 256] + be[t + 256], 0.f);
    if (MODE == 0) ((short*)out)[(size_t)row * ldo + t + 256] = f2bf(y1);
    else           ((float*)out)[(size_t)row * ldo + t + 256] = y1;
  }
}

__global__ __launch_bounds__(256) void k_ln_relu_bf16(
    const float* __restrict__ X, int W, const float* __restrict__ g,
    const float* __restrict__ be, short* __restrict__ out, int ldo) {
  ln_relu_body<0>(X, W, g, be, out, ldo);
}
__global__ __launch_bounds__(256) void k_ln_relu_f32(
    const float* __restrict__ X, int W, const float* __restrict__ g,
    const float* __restrict__ be, float* __restrict__ out, int ldo) {
  ln_relu_body<1>(X, W, g, be, out, ldo);
}

extern "C" void kernel_launch(void* const* d_in, const int* in_sizes, int n_in,
                              void* d_out, int out_size, void* d_ws, size_t ws_size,
                              hipStream_t stream) {
  const float* nf      = (const float*)d_in[0];
  const float* Mob     = (const float*)d_in[1];
  const float* W_in1   = (const float*)d_in[2];
  const float* b_in1   = (const float*)d_in[3];
  const float* W_out1  = (const float*)d_in[4];
  const float* b_out1  = (const float*)d_in[5];
  const float* W_self1 = (const float*)d_in[6];
  const float* b_self1 = (const float*)d_in[7];
  const float* g1      = (const float*)d_in[8];
  const float* be1     = (const float*)d_in[9];
  const float* W_in2   = (const float*)d_in[10];
  const float* b_in2   = (const float*)d_in[11];
  const float* W_out2  = (const float*)d_in[12];
  const float* b_out2  = (const float*)d_in[13];
  const float* W_self2 = (const float*)d_in[14];
  const float* b_self2 = (const float*)d_in[15];
  const float* g2      = (const float*)d_in[16];
  const float* be2     = (const float*)d_in[17];

  char* ws = (char*)d_ws;
  float* colsum = (float*)(ws);
  u32*   colmax = (u32*)(ws + 32768);
  short* Mt     = (short*)(ws + 65536);               // [8192][8192] bf16
  short* nft    = (short*)(ws + 134283264);           // [256][8192]
  short* A1cat  = (short*)(ws + 138477568);           // [8192][512]: [A1|nf]
  float* C2f    = (float*)(ws + 146866176);           // [8192][512] f32
  short* Acat2  = (short*)(ws + 163643392);           // [8192][768]: [agg2|h1]
  short* T2t    = (short*)(ws + 176226304);           // [256][8192]
  short* Bcat1  = (short*)(ws + 180420608);           // [512][512]: [Wc1^T|Wself1^T]
  short* Bcat2  = (short*)(ws + 180944896);           // [256][768]
  short* Win2t  = (short*)(ws + 181338112);           // [256][512]
  short* Wout1t = (short*)(ws + 181600256);           // [512][512]
  short* Win1b  = (short*)(ws + 182124544);           // [256][512]
  float* bias1c = (float*)(ws + 182386688);           // [512]
  float* bias2c = (float*)(ws + 182390784);           // [256]
  short* P1     = (short*)(ws + 188743680);           // 8 x [8192][256] bf16
  short* P2     = (short*)(ws + 222298112);           // 8 x [8192][256] bf16

  hipMemsetAsync(ws, 0, 65536, stream);  // zero colsum + colmax every call

  k_prep_all<<<9603, 256, 0, stream>>>(Mob, nf, W_in1, W_out1, W_self1, W_in2,
                                       W_out2, W_self2, b_in1, b_out1, b_self1,
                                       b_out2, b_self2, Mt, colsum, colmax, nft,
                                       A1cat, Win1b, Wout1t, Bcat1, Win2t, Bcat2,
                                       bias1c, bias2c);
  // Wc1^T = W_out1^T @ W_in1 : [512][256] into Bcat1 cols 0:256
  k_gemm_raw_n<<<dim3(4, 8), 256, 0, stream>>>(Wout1t, Win1b, 512, 512, 512,
                                               Bcat1, 512);

  // ---- layer 1 (reassociated): G1 = Mt @ nft^T  (M=8192,N=256,K=8192, z=8)
  k_gemm_sk128<<<dim3(2, 64, 8), 256, 0, stream>>>(Mt, nft, 1024, NN, NN,
                                                   P1, 256, (size_t)8192 * 256);
  k_sk_reduce_sub<<<2048, 256, 0, stream>>>(P1, 256, (size_t)8192 * 256, 8,
                                            colsum, colmax, A1cat + 256, 512,
                                            A1cat, 512);
  k_gemm_out_w<<<dim3(4, 128), 256, 0, stream>>>(A1cat, Bcat1, 512, 512, 512,
                                                 C2f, 512, bias1c);
  k_ln_relu_bf16<<<8192, 256, 0, stream>>>(C2f, 512, g1, be1, Acat2 + 256, 768);

  // ---- layer 2: T2t = W_in2^T@h1^T + b_in2; agg2; out2; LN
  k_gemm_bias_n<<<dim3(128, 4), 256, 0, stream>>>(Win2t, Acat2 + 256, 512, 512, 768,
                                                  T2t, NN, b_in2);
  k_gemm_sk128<<<dim3(2, 64, 8), 256, 0, stream>>>(Mt, T2t, 1024, NN, NN,
                                                   P2, 256, (size_t)8192 * 256);
  k_sk_reduce<<<2048, 256, 0, stream>>>(P2, 256, (size_t)8192 * 256, 8,
                                        colsum, colmax, T2t, Acat2, 768);
  k_gemm_out_n<<<dim3(4, 128), 256, 0, stream>>>(Acat2, Bcat2, 768, 768, 768,
                                                 C2f, 256, bias2c);
  k_ln_relu_f32<<<8192, 256, 0, stream>>>(C2f, 256, g2, be2, (float*)d_out, 256);
}